// Round 2
// baseline (704.626 us; speedup 1.0000x reference)
//
#include <hip/hip_runtime.h>
#include <math.h>

// Problem constants
#define DIMD 512
#define SEQ 1280      // padded sequence (SEQ_LEN+1)
#define NREAL 1279    // real rows in x / out
#define NTEXT 256
#define NIMG 1024
#define IMGW 32
#define NH 8
#define DH 64
#define BH 32         // batch*heads
#define BATCH 4
#define NKEY 305      // 256 text + 49 conv
#define FLTMAX 3.402823466e38f

// ---------------- Kernel 1: QKV projection ----------------
// x:(4,1279,512)  W:(512,1536) -> q,k,v each [bh][n][dh], q scaled by 1/8.
__global__ __launch_bounds__(256) void qkv_gemm(
    const float* __restrict__ x, const float* __restrict__ W,
    float* __restrict__ qb, float* __restrict__ kb, float* __restrict__ vb)
{
    __shared__ float As[16][64];
    __shared__ float Bs[16][64];
    const int tx = threadIdx.x, ty = threadIdx.y;
    const int tid = ty * 16 + tx;
    const int m0 = blockIdx.x * 64;   // rows (b*1280+n), M=5120
    const int n0 = blockIdx.y * 64;   // cols in [0,1536)
    float acc[4][4] = {};

    for (int k0 = 0; k0 < DIMD; k0 += 16) {
        #pragma unroll
        for (int i = 0; i < 4; i++) {
            int idx = tid + 256 * i;           // 0..1023
            int r = idx >> 4, kk = idx & 15;
            int m = m0 + r;
            int b = m / SEQ, n = m % SEQ;
            float av = 0.f;
            if (n < NREAL) av = x[((size_t)(b * NREAL + n)) * DIMD + k0 + kk];
            As[kk][r] = av;
        }
        #pragma unroll
        for (int i = 0; i < 4; i++) {
            int idx = tid + 256 * i;
            int kk = idx >> 6, c = idx & 63;
            Bs[kk][c] = W[(size_t)(k0 + kk) * 1536 + n0 + c];
        }
        __syncthreads();
        #pragma unroll
        for (int kk = 0; kk < 16; kk++) {
            float a[4], bv[4];
            #pragma unroll
            for (int i = 0; i < 4; i++) a[i] = As[kk][ty * 4 + i];
            #pragma unroll
            for (int j = 0; j < 4; j++) bv[j] = Bs[kk][tx * 4 + j];
            #pragma unroll
            for (int i = 0; i < 4; i++)
                #pragma unroll
                for (int j = 0; j < 4; j++)
                    acc[i][j] += a[i] * bv[j];
        }
        __syncthreads();
    }

    #pragma unroll
    for (int i = 0; i < 4; i++) {
        int m = m0 + ty * 4 + i;
        int b = m / SEQ, n = m % SEQ;
        #pragma unroll
        for (int j = 0; j < 4; j++) {
            int c = n0 + tx * 4 + j;
            int which = c >> 9;          // 0=q 1=k 2=v
            int h = (c >> 6) & 7;
            int dh = c & 63;
            float val = acc[i][j];
            float* dst = (which == 0) ? qb : ((which == 1) ? kb : vb);
            if (which == 0) val *= 0.125f;   // DH^-0.5
            dst[((size_t)(b * NH + h) * SEQ + n) * DH + dh] = val;
        }
    }
}

// ---------------- Kernel 2: text attention ----------------
// One wave (64 threads) per (bh, query). Causal over keys 0..qi.
__global__ __launch_bounds__(64) void attn_text(
    const float* __restrict__ qb, const float* __restrict__ kb,
    const float* __restrict__ vb, float* __restrict__ ao)
{
    const int blk = blockIdx.x;
    const int bh = blk >> 8;
    const int qi = blk & 255;
    const int lane = threadIdx.x;
    __shared__ float qs[64];
    __shared__ float ps[256];

    qs[lane] = qb[((size_t)bh * SEQ + qi) * DH + lane];
    __syncthreads();

    float pv[4];
    float lmax = -FLTMAX;
    #pragma unroll
    for (int it = 0; it < 4; it++) {
        int j = lane + it * 64;
        float dot = -FLTMAX;
        if (j <= qi) {
            const float4* k4 = reinterpret_cast<const float4*>(
                kb + ((size_t)bh * SEQ + j) * DH);
            float s = 0.f;
            #pragma unroll
            for (int d4 = 0; d4 < 16; d4++) {
                float4 kv = k4[d4];
                const float4 qv = *reinterpret_cast<const float4*>(&qs[d4 * 4]);
                s += qv.x * kv.x + qv.y * kv.y + qv.z * kv.z + qv.w * kv.w;
            }
            dot = s;
        }
        pv[it] = dot;
        lmax = fmaxf(lmax, dot);
    }
    #pragma unroll
    for (int off = 32; off; off >>= 1) lmax = fmaxf(lmax, __shfl_xor(lmax, off));
    float lsum = 0.f;
    #pragma unroll
    for (int it = 0; it < 4; it++) {
        float e = expf(pv[it] - lmax);   // masked: expf(-3.4e38) == 0
        pv[it] = e;
        lsum += e;
    }
    #pragma unroll
    for (int off = 32; off; off >>= 1) lsum += __shfl_xor(lsum, off);
    const float inv = 1.f / lsum;
    #pragma unroll
    for (int it = 0; it < 4; it++) ps[lane + it * 64] = pv[it] * inv;
    __syncthreads();

    float o = 0.f;
    for (int j = 0; j <= qi; j++)
        o += ps[j] * vb[((size_t)bh * SEQ + j) * DH + lane];

    const int b = bh >> 3, h = bh & 7;
    ao[((size_t)b * SEQ + qi) * DIMD + h * DH + lane] = o;
}

// ---------------- Kernel 3: image attention ----------------
// One wave per (bh, img query). 256 text keys (mask, int32) + 49 conv keys (causal).
__global__ __launch_bounds__(64) void attn_img(
    const float* __restrict__ qb, const float* __restrict__ kb,
    const float* __restrict__ vb, const int* __restrict__ mask,
    float* __restrict__ ao)
{
    const int blk = blockIdx.x;
    const int bh = blk >> 10;
    const int qi = blk & 1023;
    const int lane = threadIdx.x;
    const int b = bh >> 3, h = bh & 7;
    const int r = qi >> 5, c = qi & 31;
    __shared__ float qs[64];
    __shared__ float ps[320];

    qs[lane] = qb[((size_t)bh * SEQ + NTEXT + qi) * DH + lane];
    __syncthreads();

    float pv[5];
    float lmax = -FLTMAX;
    #pragma unroll
    for (int it = 0; it < 5; it++) {
        int j = lane + it * 64;
        float dot = -FLTMAX;
        const float* krow = nullptr;
        if (j < NTEXT) {
            if (mask[b * 256 + j] != 0) krow = kb + ((size_t)bh * SEQ + j) * DH;
        } else if (j < NKEY) {
            int t = j - NTEXT;
            int nr = r + t / 7 - 3, nc = c + t % 7 - 3;
            if (nr >= 0 && nr < IMGW && nc >= 0 && nc < IMGW) {
                int kidx = nr * IMGW + nc;
                if (kidx <= qi)   // causal: keep k <= q (raster order)
                    krow = kb + ((size_t)bh * SEQ + NTEXT + kidx) * DH;
            }
        }
        if (krow) {
            const float4* k4 = reinterpret_cast<const float4*>(krow);
            float s = 0.f;
            #pragma unroll
            for (int d4 = 0; d4 < 16; d4++) {
                float4 kv = k4[d4];
                const float4 qv = *reinterpret_cast<const float4*>(&qs[d4 * 4]);
                s += qv.x * kv.x + qv.y * kv.y + qv.z * kv.z + qv.w * kv.w;
            }
            dot = s;
        }
        pv[it] = dot;
        lmax = fmaxf(lmax, dot);
    }
    #pragma unroll
    for (int off = 32; off; off >>= 1) lmax = fmaxf(lmax, __shfl_xor(lmax, off));
    float lsum = 0.f;
    #pragma unroll
    for (int it = 0; it < 5; it++) {
        float e = expf(pv[it] - lmax);
        pv[it] = e;
        lsum += e;
    }
    #pragma unroll
    for (int off = 32; off; off >>= 1) lsum += __shfl_xor(lsum, off);
    const float inv = 1.f / lsum;
    #pragma unroll
    for (int it = 0; it < 5; it++) {
        int j = lane + it * 64;
        if (j < NKEY) ps[j] = pv[it] * inv;
    }
    __syncthreads();

    float o = 0.f;
    for (int j = 0; j < NTEXT; j++)
        o += ps[j] * vb[((size_t)bh * SEQ + j) * DH + lane];
    #pragma unroll
    for (int t = 0; t < 49; t++) {
        int nr = r + t / 7 - 3, nc = c + t % 7 - 3;
        if (nr >= 0 && nr < IMGW && nc >= 0 && nc < IMGW)
            o += ps[NTEXT + t] * vb[((size_t)bh * SEQ + NTEXT + nr * IMGW + nc) * DH + lane];
    }
    ao[((size_t)b * SEQ + NTEXT + qi) * DIMD + h * DH + lane] = o;
}

// ---------------- Kernel 4: output projection ----------------
// ao:[b][n][512] (n in padded 1280 space) @ W_out(512,512) + b_out -> out (4,1279,512)
__global__ __launch_bounds__(256) void out_gemm(
    const float* __restrict__ ao, const float* __restrict__ W,
    const float* __restrict__ bias, float* __restrict__ out)
{
    __shared__ float As[16][64];
    __shared__ float Bs[16][64];
    const int tx = threadIdx.x, ty = threadIdx.y;
    const int tid = ty * 16 + tx;
    const int m0 = blockIdx.x * 64;   // rows over 4*1279=5116
    const int n0 = blockIdx.y * 64;
    float acc[4][4] = {};

    for (int k0 = 0; k0 < DIMD; k0 += 16) {
        #pragma unroll
        for (int i = 0; i < 4; i++) {
            int idx = tid + 256 * i;
            int rr = idx >> 4, kk = idx & 15;
            int m = m0 + rr;
            float av = 0.f;
            if (m < BATCH * NREAL) {
                int b = m / NREAL, n = m % NREAL;
                av = ao[((size_t)b * SEQ + n) * DIMD + k0 + kk];
            }
            As[kk][rr] = av;
        }
        #pragma unroll
        for (int i = 0; i < 4; i++) {
            int idx = tid + 256 * i;
            int kk = idx >> 6, cc = idx & 63;
            Bs[kk][cc] = W[(size_t)(k0 + kk) * DIMD + n0 + cc];
        }
        __syncthreads();
        #pragma unroll
        for (int kk = 0; kk < 16; kk++) {
            float a[4], bv[4];
            #pragma unroll
            for (int i = 0; i < 4; i++) a[i] = As[kk][ty * 4 + i];
            #pragma unroll
            for (int j = 0; j < 4; j++) bv[j] = Bs[kk][tx * 4 + j];
            #pragma unroll
            for (int i = 0; i < 4; i++)
                #pragma unroll
                for (int j = 0; j < 4; j++)
                    acc[i][j] += a[i] * bv[j];
        }
        __syncthreads();
    }

    #pragma unroll
    for (int i = 0; i < 4; i++) {
        int m = m0 + ty * 4 + i;
        if (m < BATCH * NREAL) {
            #pragma unroll
            for (int j = 0; j < 4; j++) {
                int cc = n0 + tx * 4 + j;
                out[(size_t)m * DIMD + cc] = acc[i][j] + bias[cc];
            }
        }
    }
}

extern "C" void kernel_launch(void* const* d_in, const int* in_sizes, int n_in,
                              void* d_out, int out_size, void* d_ws, size_t ws_size,
                              hipStream_t stream) {
    const float* x    = (const float*)d_in[0];
    const int* mask   = (const int*)d_in[1];   // bool -> staged as int32
    const float* Wqkv = (const float*)d_in[2];
    const float* Wout = (const float*)d_in[3];
    const float* bout = (const float*)d_in[4];
    float* out = (float*)d_out;

    float* ws = (float*)d_ws;
    const size_t PER = (size_t)BH * SEQ * DH;   // 2,621,440 floats
    float* qb = ws;
    float* kb = ws + PER;
    float* vb = ws + 2 * PER;
    float* ao = ws + 3 * PER;   // total 41.9 MB of ws

    dim3 blk16(16, 16);
    qkv_gemm<<<dim3(80, 24), blk16, 0, stream>>>(x, Wqkv, qb, kb, vb);
    attn_text<<<dim3(BH * NTEXT), dim3(64), 0, stream>>>(qb, kb, vb, ao);
    attn_img<<<dim3(BH * NIMG), dim3(64), 0, stream>>>(qb, kb, vb, mask, ao);
    out_gemm<<<dim3(80, 8), blk16, 0, stream>>>(ao, Wout, bout, out);
}

// Round 3
// 332.568 us; speedup vs baseline: 2.1187x; 2.1187x over previous
//
#include <hip/hip_runtime.h>
#include <math.h>

#define DIMD 512
#define SEQ 1280
#define NREAL 1279
#define NTEXT 256
#define NIMG 1024
#define IMGW 32
#define NH 8
#define DH 64
#define BH 32
#define BATCH 4
#define VTW 1344            // Vt padded key width (SEQ + 64)
#define FLTMAX 3.402823466e38f

typedef __attribute__((ext_vector_type(8))) short short8;
typedef __attribute__((ext_vector_type(4))) float f32x4;
typedef __attribute__((ext_vector_type(4))) unsigned short ushort4v;

#define MFMA16(a, b, c) __builtin_amdgcn_mfma_f32_16x16x32_bf16((a), (b), (c), 0, 0, 0)

__device__ __forceinline__ unsigned short f2bf(float x) {
    unsigned int u = __builtin_bit_cast(unsigned int, x);
    u += 0x7fffu + ((u >> 16) & 1u);
    return (unsigned short)(u >> 16);
}

// ---------------- Kernel 1: QKV projection (fp32 compute, bf16 outputs) ----
// x:(4,1279,512) @ W(512,1536) -> qb16,kb16 [bh][1280][64] bf16 (q scaled),
// vt16 [bh][64][VTW] bf16 (V transposed, keys padded to VTW).
__global__ __launch_bounds__(256) void qkv_gemm(
    const float* __restrict__ x, const float* __restrict__ W,
    unsigned short* __restrict__ qb, unsigned short* __restrict__ kb,
    unsigned short* __restrict__ vt)
{
    __shared__ float As[16][64];
    __shared__ float Bs[16][64];
    const int tx = threadIdx.x, ty = threadIdx.y;
    const int tid = ty * 16 + tx;
    const int m0 = blockIdx.x * 64;   // rows (b*1280+n), M=5120
    const int n0 = blockIdx.y * 64;   // cols in [0,1536)
    float acc[4][4] = {};

    for (int k0 = 0; k0 < DIMD; k0 += 16) {
        #pragma unroll
        for (int i = 0; i < 4; i++) {
            int idx = tid + 256 * i;
            int r = idx >> 4, kk = idx & 15;
            int m = m0 + r;
            int b = m / SEQ, n = m % SEQ;
            float av = 0.f;
            if (n < NREAL) av = x[((size_t)(b * NREAL + n)) * DIMD + k0 + kk];
            As[kk][r] = av;
        }
        #pragma unroll
        for (int i = 0; i < 4; i++) {
            int idx = tid + 256 * i;
            int kk = idx >> 6, c = idx & 63;
            Bs[kk][c] = W[(size_t)(k0 + kk) * 1536 + n0 + c];
        }
        __syncthreads();
        #pragma unroll
        for (int kk = 0; kk < 16; kk++) {
            float a[4], bv[4];
            #pragma unroll
            for (int i = 0; i < 4; i++) a[i] = As[kk][ty * 4 + i];
            #pragma unroll
            for (int j = 0; j < 4; j++) bv[j] = Bs[kk][tx * 4 + j];
            #pragma unroll
            for (int i = 0; i < 4; i++)
                #pragma unroll
                for (int j = 0; j < 4; j++)
                    acc[i][j] += a[i] * bv[j];
        }
        __syncthreads();
    }

    const int which = n0 >> 9;          // 0=q 1=k 2=v (n0 multiple of 64)
    const int h = (n0 >> 6) & 7;
    const int dh0 = tx * 4;

    if (which == 2) {
        // Vt: pack 4 consecutive n per dim column (same batch: 64 | 1280)
        int m = m0 + ty * 4;
        int b = m / SEQ, n = m % SEQ;
        int bh = b * NH + h;
        #pragma unroll
        for (int j = 0; j < 4; j++) {
            ushort4v pk;
            #pragma unroll
            for (int i = 0; i < 4; i++) pk[i] = f2bf(acc[i][j]);
            *reinterpret_cast<ushort4v*>(vt + ((size_t)bh * DH + dh0 + j) * VTW + n) = pk;
        }
    } else {
        unsigned short* dst = (which == 0) ? qb : kb;
        const float sc = (which == 0) ? 0.125f : 1.f;
        #pragma unroll
        for (int i = 0; i < 4; i++) {
            int m = m0 + ty * 4 + i;
            int b = m / SEQ, n = m % SEQ;
            int bh = b * NH + h;
            ushort4v pk;
            #pragma unroll
            for (int j = 0; j < 4; j++) pk[j] = f2bf(acc[i][j] * sc);
            *reinterpret_cast<ushort4v*>(dst + ((size_t)bh * SEQ + n) * DH + dh0) = pk;
        }
    }
}

// ---------------- Kernel 2: text attention (MFMA) ----------------
// One wave per (bh, 16-query tile t). Causal over 256 text keys.
__global__ __launch_bounds__(64) void attn_text2(
    const unsigned short* __restrict__ qb, const unsigned short* __restrict__ kb,
    const unsigned short* __restrict__ vt, float* __restrict__ ao)
{
    __shared__ __align__(16) unsigned short P[16 * 264];  // exp(S), bf16
    const int blk = blockIdx.x;
    const int bh = blk >> 4;
    const int t = blk & 15;
    const int lane = threadIdx.x;
    const int g = lane >> 4, col = lane & 15;
    const int b = bh >> 3, h = bh & 7;

    const size_t qrow = (size_t)bh * SEQ + t * 16 + col;
    const short8 qa0 = *reinterpret_cast<const short8*>(qb + qrow * DH + g * 8);
    const short8 qa1 = *reinterpret_cast<const short8*>(qb + qrow * DH + 32 + g * 8);

    f32x4 st[16];
    #pragma unroll
    for (int kt = 0; kt < 16; kt++) {
        if (kt <= t) {
            size_t krow = (size_t)bh * SEQ + kt * 16 + col;
            short8 kb0 = *reinterpret_cast<const short8*>(kb + krow * DH + g * 8);
            short8 kb1 = *reinterpret_cast<const short8*>(kb + krow * DH + 32 + g * 8);
            f32x4 s = {0.f, 0.f, 0.f, 0.f};
            s = MFMA16(qa0, kb0, s);
            s = MFMA16(qa1, kb1, s);
            if (kt == t) {
                #pragma unroll
                for (int rr = 0; rr < 4; rr++)
                    if (col > 4 * g + rr) s[rr] = -FLTMAX;
            }
            st[kt] = s;
        }
    }

    float m[4] = {-FLTMAX, -FLTMAX, -FLTMAX, -FLTMAX};
    #pragma unroll
    for (int kt = 0; kt < 16; kt++)
        if (kt <= t)
            #pragma unroll
            for (int rr = 0; rr < 4; rr++) m[rr] = fmaxf(m[rr], st[kt][rr]);
    #pragma unroll
    for (int rr = 0; rr < 4; rr++) {
        m[rr] = fmaxf(m[rr], __shfl_xor(m[rr], 1));
        m[rr] = fmaxf(m[rr], __shfl_xor(m[rr], 2));
        m[rr] = fmaxf(m[rr], __shfl_xor(m[rr], 4));
        m[rr] = fmaxf(m[rr], __shfl_xor(m[rr], 8));
    }
    float ssum[4] = {0.f, 0.f, 0.f, 0.f};
    #pragma unroll
    for (int kt = 0; kt < 16; kt++)
        if (kt <= t) {
            #pragma unroll
            for (int rr = 0; rr < 4; rr++) {
                float e = expf(st[kt][rr] - m[rr]);
                st[kt][rr] = e;
                ssum[rr] += e;
            }
        }
    #pragma unroll
    for (int rr = 0; rr < 4; rr++) {
        ssum[rr] += __shfl_xor(ssum[rr], 1);
        ssum[rr] += __shfl_xor(ssum[rr], 2);
        ssum[rr] += __shfl_xor(ssum[rr], 4);
        ssum[rr] += __shfl_xor(ssum[rr], 8);
    }

    // write P (bf16)
    #pragma unroll
    for (int kt = 0; kt < 16; kt++)
        if (kt <= t) {
            #pragma unroll
            for (int rr = 0; rr < 4; rr++)
                P[(4 * g + rr) * 264 + kt * 16 + col] = f2bf(st[kt][rr]);
        }
    // zero the boundary tile kt=t+1 when t even (PV k-block covers it)
    if ((t & 1) == 0) {
        ushort4v z = {0, 0, 0, 0};
        *reinterpret_cast<ushort4v*>(
            &P[(lane >> 2) * 264 + (t + 1) * 16 + (lane & 3) * 4]) = z;
    }
    __syncthreads();

    f32x4 acc[4] = {};
    #pragma unroll
    for (int kkb = 0; kkb < 8; kkb++) {
        if (kkb <= (t >> 1)) {
            short8 pa = *reinterpret_cast<const short8*>(&P[col * 264 + kkb * 32 + g * 8]);
            #pragma unroll
            for (int n0t = 0; n0t < 4; n0t++) {
                short8 vb = *reinterpret_cast<const short8*>(
                    vt + ((size_t)bh * DH + n0t * 16 + col) * VTW + kkb * 32 + g * 8);
                acc[n0t] = MFMA16(pa, vb, acc[n0t]);
            }
        }
    }

    #pragma unroll
    for (int rr = 0; rr < 4; rr++) {
        int qrow_o = t * 16 + 4 * g + rr;
        float inv = 1.f / ssum[rr];
        #pragma unroll
        for (int n0t = 0; n0t < 4; n0t++)
            ao[((size_t)b * SEQ + qrow_o) * DIMD + h * DH + n0t * 16 + col] =
                acc[n0t][rr] * inv;
    }
}

// ---------------- Kernel 3: image attention (MFMA) ----------------
// One wave per (bh, 16-query tile). 256 text keys (mask) + 7x7 conv window
// (causality => only rows r-3..r survive).
__global__ __launch_bounds__(64) void attn_img2(
    const unsigned short* __restrict__ qb, const unsigned short* __restrict__ kb,
    const unsigned short* __restrict__ vt, const int* __restrict__ mask,
    float* __restrict__ ao)
{
    __shared__ __align__(16) unsigned short P[16 * 392];  // 256 text + 4*32 window
    const int blk = blockIdx.x;
    const int bh = blk >> 6;
    const int tile = blk & 63;
    const int r = tile >> 1, c0 = (tile & 1) << 4;
    const int lane = threadIdx.x;
    const int g = lane >> 4, col = lane & 15;
    const int b = bh >> 3, h = bh & 7;

    const size_t qrow = (size_t)bh * SEQ + NTEXT + r * 32 + c0 + col;
    const short8 qa0 = *reinterpret_cast<const short8*>(qb + qrow * DH + g * 8);
    const short8 qa1 = *reinterpret_cast<const short8*>(qb + qrow * DH + 32 + g * 8);

    // ---- text scores ----
    f32x4 st[16];
    #pragma unroll
    for (int kt = 0; kt < 16; kt++) {
        int j = kt * 16 + col;
        size_t krow = (size_t)bh * SEQ + j;
        short8 kb0 = *reinterpret_cast<const short8*>(kb + krow * DH + g * 8);
        short8 kb1 = *reinterpret_cast<const short8*>(kb + krow * DH + 32 + g * 8);
        f32x4 s = {0.f, 0.f, 0.f, 0.f};
        s = MFMA16(qa0, kb0, s);
        s = MFMA16(qa1, kb1, s);
        if (mask[b * 256 + j] == 0) {
            #pragma unroll
            for (int rr = 0; rr < 4; rr++) s[rr] = -FLTMAX;
        }
        st[kt] = s;
    }

    // ---- conv window scores: rows r-3..r, cols c0-8..c0+23 (32 wide) ----
    f32x4 sw[4][2];
    bool wvalid[4];
    #pragma unroll
    for (int w = 0; w < 4; w++) {
        int nr = r - 3 + w;
        wvalid[w] = (nr >= 0);
        if (nr >= 0) {
            #pragma unroll
            for (int ct = 0; ct < 2; ct++) {
                int nc = c0 - 8 + ct * 16 + col;
                int ncc = min(max(nc, 0), IMGW - 1);
                size_t krow = (size_t)bh * SEQ + NTEXT + nr * IMGW + ncc;
                short8 kb0 = *reinterpret_cast<const short8*>(kb + krow * DH + g * 8);
                short8 kb1 = *reinterpret_cast<const short8*>(kb + krow * DH + 32 + g * 8);
                f32x4 s = {0.f, 0.f, 0.f, 0.f};
                s = MFMA16(qa0, kb0, s);
                s = MFMA16(qa1, kb1, s);
                #pragma unroll
                for (int rr = 0; rr < 4; rr++) {
                    int q = 4 * g + rr;            // local query 0..15
                    int dnc = nc - (c0 + q);       // nc - c
                    bool ok = (nc >= 0) && (nc < IMGW) && (dnc >= -3) &&
                              (dnc <= ((w == 3) ? 0 : 3));
                    if (!ok) s[rr] = -FLTMAX;
                }
                sw[w][ct] = s;
            }
        }
    }

    // ---- softmax ----
    float m[4] = {-FLTMAX, -FLTMAX, -FLTMAX, -FLTMAX};
    #pragma unroll
    for (int kt = 0; kt < 16; kt++)
        #pragma unroll
        for (int rr = 0; rr < 4; rr++) m[rr] = fmaxf(m[rr], st[kt][rr]);
    #pragma unroll
    for (int w = 0; w < 4; w++)
        if (wvalid[w])
            #pragma unroll
            for (int ct = 0; ct < 2; ct++)
                #pragma unroll
                for (int rr = 0; rr < 4; rr++) m[rr] = fmaxf(m[rr], sw[w][ct][rr]);
    #pragma unroll
    for (int rr = 0; rr < 4; rr++) {
        m[rr] = fmaxf(m[rr], __shfl_xor(m[rr], 1));
        m[rr] = fmaxf(m[rr], __shfl_xor(m[rr], 2));
        m[rr] = fmaxf(m[rr], __shfl_xor(m[rr], 4));
        m[rr] = fmaxf(m[rr], __shfl_xor(m[rr], 8));
    }
    float ssum[4] = {0.f, 0.f, 0.f, 0.f};
    #pragma unroll
    for (int kt = 0; kt < 16; kt++)
        #pragma unroll
        for (int rr = 0; rr < 4; rr++) {
            float e = expf(st[kt][rr] - m[rr]);
            st[kt][rr] = e;
            ssum[rr] += e;
        }
    #pragma unroll
    for (int w = 0; w < 4; w++)
        if (wvalid[w])
            #pragma unroll
            for (int ct = 0; ct < 2; ct++)
                #pragma unroll
                for (int rr = 0; rr < 4; rr++) {
                    float e = expf(sw[w][ct][rr] - m[rr]);
                    sw[w][ct][rr] = e;
                    ssum[rr] += e;
                }
    #pragma unroll
    for (int rr = 0; rr < 4; rr++) {
        ssum[rr] += __shfl_xor(ssum[rr], 1);
        ssum[rr] += __shfl_xor(ssum[rr], 2);
        ssum[rr] += __shfl_xor(ssum[rr], 4);
        ssum[rr] += __shfl_xor(ssum[rr], 8);
    }

    // ---- write P ----
    #pragma unroll
    for (int kt = 0; kt < 16; kt++)
        #pragma unroll
        for (int rr = 0; rr < 4; rr++)
            P[(4 * g + rr) * 392 + kt * 16 + col] = f2bf(st[kt][rr]);
    #pragma unroll
    for (int w = 0; w < 4; w++)
        if (wvalid[w])
            #pragma unroll
            for (int ct = 0; ct < 2; ct++)
                #pragma unroll
                for (int rr = 0; rr < 4; rr++)
                    P[(4 * g + rr) * 392 + 256 + w * 32 + ct * 16 + col] =
                        f2bf(sw[w][ct][rr]);
    __syncthreads();

    // ---- PV ----
    f32x4 acc[4] = {};
    #pragma unroll
    for (int kkb = 0; kkb < 8; kkb++) {
        short8 pa = *reinterpret_cast<const short8*>(&P[col * 392 + kkb * 32 + g * 8]);
        #pragma unroll
        for (int n0t = 0; n0t < 4; n0t++) {
            short8 vb = *reinterpret_cast<const short8*>(
                vt + ((size_t)bh * DH + n0t * 16 + col) * VTW + kkb * 32 + g * 8);
            acc[n0t] = MFMA16(pa, vb, acc[n0t]);
        }
    }
    #pragma unroll
    for (int w = 0; w < 4; w++) {
        if (wvalid[w]) {
            int nr = r - 3 + w;
            short8 pa = *reinterpret_cast<const short8*>(&P[col * 392 + 256 + w * 32 + g * 8]);
            size_t vkey = (size_t)(NTEXT + nr * IMGW + c0 - 8 + g * 8);
            #pragma unroll
            for (int n0t = 0; n0t < 4; n0t++) {
                short8 vb = *reinterpret_cast<const short8*>(
                    vt + ((size_t)bh * DH + n0t * 16 + col) * VTW + vkey);
                acc[n0t] = MFMA16(pa, vb, acc[n0t]);
            }
        }
    }

    #pragma unroll
    for (int rr = 0; rr < 4; rr++) {
        int qrow_o = NTEXT + r * IMGW + c0 + 4 * g + rr;
        float inv = 1.f / ssum[rr];
        #pragma unroll
        for (int n0t = 0; n0t < 4; n0t++)
            ao[((size_t)b * SEQ + qrow_o) * DIMD + h * DH + n0t * 16 + col] =
                acc[n0t][rr] * inv;
    }
}

// ---------------- Kernel 4: output projection (fp32) ----------------
__global__ __launch_bounds__(256) void out_gemm(
    const float* __restrict__ ao, const float* __restrict__ W,
    const float* __restrict__ bias, float* __restrict__ out)
{
    __shared__ float As[16][64];
    __shared__ float Bs[16][64];
    const int tx = threadIdx.x, ty = threadIdx.y;
    const int tid = ty * 16 + tx;
    const int m0 = blockIdx.x * 64;
    const int n0 = blockIdx.y * 64;
    float acc[4][4] = {};

    for (int k0 = 0; k0 < DIMD; k0 += 16) {
        #pragma unroll
        for (int i = 0; i < 4; i++) {
            int idx = tid + 256 * i;
            int rr = idx >> 4, kk = idx & 15;
            int m = m0 + rr;
            float av = 0.f;
            if (m < BATCH * NREAL) {
                int b = m / NREAL, n = m % NREAL;
                av = ao[((size_t)b * SEQ + n) * DIMD + k0 + kk];
            }
            As[kk][rr] = av;
        }
        #pragma unroll
        for (int i = 0; i < 4; i++) {
            int idx = tid + 256 * i;
            int kk = idx >> 6, cc = idx & 63;
            Bs[kk][cc] = W[(size_t)(k0 + kk) * DIMD + n0 + cc];
        }
        __syncthreads();
        #pragma unroll
        for (int kk = 0; kk < 16; kk++) {
            float a[4], bv[4];
            #pragma unroll
            for (int i = 0; i < 4; i++) a[i] = As[kk][ty * 4 + i];
            #pragma unroll
            for (int j = 0; j < 4; j++) bv[j] = Bs[kk][tx * 4 + j];
            #pragma unroll
            for (int i = 0; i < 4; i++)
                #pragma unroll
                for (int j = 0; j < 4; j++)
                    acc[i][j] += a[i] * bv[j];
        }
        __syncthreads();
    }

    #pragma unroll
    for (int i = 0; i < 4; i++) {
        int m = m0 + ty * 4 + i;
        if (m < BATCH * NREAL) {
            #pragma unroll
            for (int j = 0; j < 4; j++) {
                int cc = n0 + tx * 4 + j;
                out[(size_t)m * DIMD + cc] = acc[i][j] + bias[cc];
            }
        }
    }
}

extern "C" void kernel_launch(void* const* d_in, const int* in_sizes, int n_in,
                              void* d_out, int out_size, void* d_ws, size_t ws_size,
                              hipStream_t stream) {
    const float* x    = (const float*)d_in[0];
    const int* mask   = (const int*)d_in[1];
    const float* Wqkv = (const float*)d_in[2];
    const float* Wout = (const float*)d_in[3];
    const float* bout = (const float*)d_in[4];
    float* out = (float*)d_out;

    const size_t PER = (size_t)BH * SEQ * DH;       // 2,621,440
    const size_t VTE = (size_t)BH * DH * VTW;       // 2,752,512
    unsigned short* qb16 = (unsigned short*)d_ws;
    unsigned short* kb16 = qb16 + PER;
    unsigned short* vt16 = kb16 + PER;
    float* ao = (float*)(vt16 + VTE);               // 4*1280*512 f32

    dim3 blk16(16, 16);
    qkv_gemm<<<dim3(80, 24), blk16, 0, stream>>>(x, Wqkv, qb16, kb16, vt16);
    attn_text2<<<dim3(BH * 16), dim3(64), 0, stream>>>(qb16, kb16, vt16, ao);
    attn_img2<<<dim3(BH * 64), dim3(64), 0, stream>>>(qb16, kb16, vt16, mask, ao);
    out_gemm<<<dim3(80, 8), blk16, 0, stream>>>(ao, Wout, bout, out);
}

// Round 4
// 152.022 us; speedup vs baseline: 4.6350x; 2.1876x over previous
//
#include <hip/hip_runtime.h>
#include <math.h>

#define DIMD 512
#define SEQ 1280
#define NREAL 1279
#define NTEXT 256
#define NIMG 1024
#define IMGW 32
#define NH 8
#define DH 64
#define BH 32
#define BATCH 4
#define VTW 1344            // Vt padded key width (SEQ + 64)
#define FLTMAX 3.402823466e38f

typedef __attribute__((ext_vector_type(8))) short short8;
typedef __attribute__((ext_vector_type(4))) float f32x4;
typedef __attribute__((ext_vector_type(4))) unsigned short ushort4v;
typedef __attribute__((ext_vector_type(8))) unsigned short ushort8v;

#define MFMA16(a, b, c) __builtin_amdgcn_mfma_f32_16x16x32_bf16((a), (b), (c), 0, 0, 0)

__device__ __forceinline__ unsigned short f2bf(float x) {
    unsigned int u = __builtin_bit_cast(unsigned int, x);
    u += 0x7fffu + ((u >> 16) & 1u);
    return (unsigned short)(u >> 16);
}

__device__ __forceinline__ void gload16(const unsigned short* g, unsigned short* l) {
    __builtin_amdgcn_global_load_lds(
        (const __attribute__((address_space(1))) unsigned int*)g,
        (__attribute__((address_space(3))) unsigned int*)l,
        16, 0, 0);
}

// ---------------- Kernel 0a: x -> bf16, padded to [5120][512] ----------------
__global__ __launch_bounds__(256) void convert_x(
    const float* __restrict__ x, unsigned short* __restrict__ xb)
{
    const size_t t = (size_t)blockIdx.x * 256 + threadIdx.x;   // 0..327679
    const size_t e0 = t * 8;
    const int row = (int)(e0 >> 9);
    const int d = (int)(e0 & 511);
    const int b = row / SEQ;
    const int ns = row - b * SEQ;
    ushort8v o;
    if (ns < NREAL) {
        const float4* p = reinterpret_cast<const float4*>(
            x + ((size_t)b * NREAL + ns) * DIMD + d);
        float4 v0 = p[0], v1 = p[1];
        o[0] = f2bf(v0.x); o[1] = f2bf(v0.y); o[2] = f2bf(v0.z); o[3] = f2bf(v0.w);
        o[4] = f2bf(v1.x); o[5] = f2bf(v1.y); o[6] = f2bf(v1.z); o[7] = f2bf(v1.w);
    } else {
        o = ushort8v{0, 0, 0, 0, 0, 0, 0, 0};
    }
    *reinterpret_cast<ushort8v*>(xb + e0) = o;
}

// ---------------- Kernel 0b: W[512][N] f32 -> Wt[N][512] bf16 ----------------
__global__ __launch_bounds__(256) void convert_transpose(
    const float* __restrict__ W, unsigned short* __restrict__ Wt, int N)
{
    __shared__ unsigned short lds[64 * 65];
    const int k0 = blockIdx.x * 64, n0 = blockIdx.y * 64;
    const int t = threadIdx.x;
    #pragma unroll
    for (int i = 0; i < 4; i++) {
        int idx = t + 256 * i;
        int r = idx >> 4, c4 = (idx & 15) * 4;
        float4 v = *reinterpret_cast<const float4*>(W + (size_t)(k0 + r) * N + n0 + c4);
        lds[(c4 + 0) * 65 + r] = f2bf(v.x);
        lds[(c4 + 1) * 65 + r] = f2bf(v.y);
        lds[(c4 + 2) * 65 + r] = f2bf(v.z);
        lds[(c4 + 3) * 65 + r] = f2bf(v.w);
    }
    __syncthreads();
    #pragma unroll
    for (int i = 0; i < 4; i++) {
        int idx = t + 256 * i;
        int n = idx >> 4, k4 = (idx & 15) * 4;
        ushort4v o;
        #pragma unroll
        for (int j = 0; j < 4; j++) o[j] = lds[n * 65 + k4 + j];
        *reinterpret_cast<ushort4v*>(Wt + (size_t)(n0 + n) * 512 + k0 + k4) = o;
    }
}

// ---------------- MFMA GEMM: C[128x128] = A[M][512] x Bt[N][512]^T ----------
// EPI 0: qkv routing epilogue (q scaled, k row-major, v transposed)
// EPI 1: out = C + bias, rows < 1279 per batch
template<int EPI>
__global__ __launch_bounds__(256) void mfma_gemm(
    const unsigned short* __restrict__ A, const unsigned short* __restrict__ Bt,
    unsigned short* __restrict__ qb, unsigned short* __restrict__ kb,
    unsigned short* __restrict__ vt,
    const float* __restrict__ bias, float* __restrict__ out)
{
    __shared__ __align__(16) unsigned short As[128 * 64];
    __shared__ __align__(16) unsigned short Bs[128 * 64];
    const int tid = threadIdx.x;
    const int lane = tid & 63, w = tid >> 6;
    const int wm = w >> 1, wn = w & 1;
    const int g = lane >> 4, col = lane & 15;
    const int m0 = blockIdx.x * 128, n0 = blockIdx.y * 128;

    char* AsB = (char*)&As[0];
    char* BsB = (char*)&Bs[0];

    f32x4 acc[4][4] = {};

    for (int ks = 0; ks < 8; ks++) {
        const int k0 = ks * 64;
        // stage: linear LDS dest, swizzled global source (slot ^= row&7)
        #pragma unroll
        for (int j = 0; j < 4; j++) {
            int rbase = w * 32 + j * 8;
            int r = rbase + (lane >> 3);
            int sl = lane & 7;
            int cs = sl ^ (r & 7);
            gload16(A + (size_t)(m0 + r) * 512 + k0 + cs * 8,
                    (unsigned short*)(AsB + rbase * 128));
            gload16(Bt + (size_t)(n0 + r) * 512 + k0 + cs * 8,
                    (unsigned short*)(BsB + rbase * 128));
        }
        __syncthreads();

        short8 af[4][2], bfr[4][2];
        #pragma unroll
        for (int mi = 0; mi < 4; mi++) {
            int rA = wm * 64 + mi * 16 + col;
            #pragma unroll
            for (int kk = 0; kk < 2; kk++) {
                int sl = (kk * 4 + g) ^ (rA & 7);
                af[mi][kk] = *reinterpret_cast<const short8*>(AsB + rA * 128 + sl * 16);
            }
        }
        #pragma unroll
        for (int ni = 0; ni < 4; ni++) {
            int rB = wn * 64 + ni * 16 + col;
            #pragma unroll
            for (int kk = 0; kk < 2; kk++) {
                int sl = (kk * 4 + g) ^ (rB & 7);
                bfr[ni][kk] = *reinterpret_cast<const short8*>(BsB + rB * 128 + sl * 16);
            }
        }
        #pragma unroll
        for (int kk = 0; kk < 2; kk++)
            #pragma unroll
            for (int mi = 0; mi < 4; mi++)
                #pragma unroll
                for (int ni = 0; ni < 4; ni++)
                    acc[mi][ni] = MFMA16(af[mi][kk], bfr[ni][kk], acc[mi][ni]);
        __syncthreads();
    }

    const int b = blockIdx.x / 10;          // 1280 rows per batch, 128-row blocks
    const int nb = m0 - b * SEQ;

    if (EPI == 0) {
        #pragma unroll
        for (int ni = 0; ni < 4; ni++) {
            const int n = n0 + wn * 64 + ni * 16 + col;
            const int which = n >> 9;
            const int h = (n >> 6) & 7;
            const int dh = n & 63;
            const int bh = b * NH + h;
            #pragma unroll
            for (int mi = 0; mi < 4; mi++) {
                const int ns0 = nb + wm * 64 + mi * 16 + 4 * g;
                if (which == 2) {
                    ushort4v pk;
                    #pragma unroll
                    for (int rr = 0; rr < 4; rr++) pk[rr] = f2bf(acc[mi][ni][rr]);
                    *reinterpret_cast<ushort4v*>(
                        vt + ((size_t)bh * DH + dh) * VTW + ns0) = pk;
                } else {
                    unsigned short* dst = which ? kb : qb;
                    const float sc = which ? 1.f : 0.125f;
                    #pragma unroll
                    for (int rr = 0; rr < 4; rr++)
                        dst[((size_t)bh * SEQ + ns0 + rr) * DH + dh] =
                            f2bf(acc[mi][ni][rr] * sc);
                }
            }
        }
    } else {
        #pragma unroll
        for (int ni = 0; ni < 4; ni++) {
            const int n = n0 + wn * 64 + ni * 16 + col;
            const float bv = bias[n];
            #pragma unroll
            for (int mi = 0; mi < 4; mi++) {
                const int ns0 = nb + wm * 64 + mi * 16 + 4 * g;
                #pragma unroll
                for (int rr = 0; rr < 4; rr++) {
                    int ns = ns0 + rr;
                    if (ns < NREAL)
                        out[((size_t)b * NREAL + ns) * DIMD + n] = acc[mi][ni][rr] + bv;
                }
            }
        }
    }
}

// ---------------- Text attention (MFMA) ----------------
__global__ __launch_bounds__(64) void attn_text2(
    const unsigned short* __restrict__ qb, const unsigned short* __restrict__ kb,
    const unsigned short* __restrict__ vt, unsigned short* __restrict__ ao)
{
    __shared__ __align__(16) unsigned short P[16 * 264];
    const int blk = blockIdx.x;
    const int bh = blk >> 4;
    const int t = blk & 15;
    const int lane = threadIdx.x;
    const int g = lane >> 4, col = lane & 15;
    const int b = bh >> 3, h = bh & 7;

    const size_t qrow = (size_t)bh * SEQ + t * 16 + col;
    const short8 qa0 = *reinterpret_cast<const short8*>(qb + qrow * DH + g * 8);
    const short8 qa1 = *reinterpret_cast<const short8*>(qb + qrow * DH + 32 + g * 8);

    f32x4 st[16];
    #pragma unroll
    for (int kt = 0; kt < 16; kt++) {
        if (kt <= t) {
            size_t krow = (size_t)bh * SEQ + kt * 16 + col;
            short8 kb0 = *reinterpret_cast<const short8*>(kb + krow * DH + g * 8);
            short8 kb1 = *reinterpret_cast<const short8*>(kb + krow * DH + 32 + g * 8);
            f32x4 s = {0.f, 0.f, 0.f, 0.f};
            s = MFMA16(qa0, kb0, s);
            s = MFMA16(qa1, kb1, s);
            if (kt == t) {
                #pragma unroll
                for (int rr = 0; rr < 4; rr++)
                    if (col > 4 * g + rr) s[rr] = -FLTMAX;
            }
            st[kt] = s;
        }
    }

    float m[4] = {-FLTMAX, -FLTMAX, -FLTMAX, -FLTMAX};
    #pragma unroll
    for (int kt = 0; kt < 16; kt++)
        if (kt <= t)
            #pragma unroll
            for (int rr = 0; rr < 4; rr++) m[rr] = fmaxf(m[rr], st[kt][rr]);
    #pragma unroll
    for (int rr = 0; rr < 4; rr++) {
        m[rr] = fmaxf(m[rr], __shfl_xor(m[rr], 1));
        m[rr] = fmaxf(m[rr], __shfl_xor(m[rr], 2));
        m[rr] = fmaxf(m[rr], __shfl_xor(m[rr], 4));
        m[rr] = fmaxf(m[rr], __shfl_xor(m[rr], 8));
    }
    float ssum[4] = {0.f, 0.f, 0.f, 0.f};
    #pragma unroll
    for (int kt = 0; kt < 16; kt++)
        if (kt <= t) {
            #pragma unroll
            for (int rr = 0; rr < 4; rr++) {
                float e = expf(st[kt][rr] - m[rr]);
                st[kt][rr] = e;
                ssum[rr] += e;
            }
        }
    #pragma unroll
    for (int rr = 0; rr < 4; rr++) {
        ssum[rr] += __shfl_xor(ssum[rr], 1);
        ssum[rr] += __shfl_xor(ssum[rr], 2);
        ssum[rr] += __shfl_xor(ssum[rr], 4);
        ssum[rr] += __shfl_xor(ssum[rr], 8);
    }

    #pragma unroll
    for (int kt = 0; kt < 16; kt++)
        if (kt <= t) {
            #pragma unroll
            for (int rr = 0; rr < 4; rr++)
                P[(4 * g + rr) * 264 + kt * 16 + col] = f2bf(st[kt][rr]);
        }
    if ((t & 1) == 0) {
        ushort4v z = {0, 0, 0, 0};
        *reinterpret_cast<ushort4v*>(
            &P[(lane >> 2) * 264 + (t + 1) * 16 + (lane & 3) * 4]) = z;
    }
    __syncthreads();

    f32x4 acc[4] = {};
    #pragma unroll
    for (int kkb = 0; kkb < 8; kkb++) {
        if (kkb <= (t >> 1)) {
            short8 pa = *reinterpret_cast<const short8*>(&P[col * 264 + kkb * 32 + g * 8]);
            #pragma unroll
            for (int n0t = 0; n0t < 4; n0t++) {
                short8 vb = *reinterpret_cast<const short8*>(
                    vt + ((size_t)bh * DH + n0t * 16 + col) * VTW + kkb * 32 + g * 8);
                acc[n0t] = MFMA16(pa, vb, acc[n0t]);
            }
        }
    }

    #pragma unroll
    for (int rr = 0; rr < 4; rr++) {
        int qrow_o = t * 16 + 4 * g + rr;
        float inv = 1.f / ssum[rr];
        #pragma unroll
        for (int n0t = 0; n0t < 4; n0t++)
            ao[((size_t)b * SEQ + qrow_o) * DIMD + h * DH + n0t * 16 + col] =
                f2bf(acc[n0t][rr] * inv);
    }
}

// ---------------- Image attention (MFMA) ----------------
__global__ __launch_bounds__(64) void attn_img2(
    const unsigned short* __restrict__ qb, const unsigned short* __restrict__ kb,
    const unsigned short* __restrict__ vt, const int* __restrict__ mask,
    unsigned short* __restrict__ ao)
{
    __shared__ __align__(16) unsigned short P[16 * 392];
    const int blk = blockIdx.x;
    const int bh = blk >> 6;
    const int tile = blk & 63;
    const int r = tile >> 1, c0 = (tile & 1) << 4;
    const int lane = threadIdx.x;
    const int g = lane >> 4, col = lane & 15;
    const int b = bh >> 3, h = bh & 7;

    const size_t qrow = (size_t)bh * SEQ + NTEXT + r * 32 + c0 + col;
    const short8 qa0 = *reinterpret_cast<const short8*>(qb + qrow * DH + g * 8);
    const short8 qa1 = *reinterpret_cast<const short8*>(qb + qrow * DH + 32 + g * 8);

    f32x4 st[16];
    #pragma unroll
    for (int kt = 0; kt < 16; kt++) {
        int j = kt * 16 + col;
        size_t krow = (size_t)bh * SEQ + j;
        short8 kb0 = *reinterpret_cast<const short8*>(kb + krow * DH + g * 8);
        short8 kb1 = *reinterpret_cast<const short8*>(kb + krow * DH + 32 + g * 8);
        f32x4 s = {0.f, 0.f, 0.f, 0.f};
        s = MFMA16(qa0, kb0, s);
        s = MFMA16(qa1, kb1, s);
        if (mask[b * 256 + j] == 0) {
            #pragma unroll
            for (int rr = 0; rr < 4; rr++) s[rr] = -FLTMAX;
        }
        st[kt] = s;
    }

    f32x4 sw[4][2];
    bool wvalid[4];
    #pragma unroll
    for (int w = 0; w < 4; w++) {
        int nr = r - 3 + w;
        wvalid[w] = (nr >= 0);
        if (nr >= 0) {
            #pragma unroll
            for (int ct = 0; ct < 2; ct++) {
                int nc = c0 - 8 + ct * 16 + col;
                int ncc = min(max(nc, 0), IMGW - 1);
                size_t krow = (size_t)bh * SEQ + NTEXT + nr * IMGW + ncc;
                short8 kb0 = *reinterpret_cast<const short8*>(kb + krow * DH + g * 8);
                short8 kb1 = *reinterpret_cast<const short8*>(kb + krow * DH + 32 + g * 8);
                f32x4 s = {0.f, 0.f, 0.f, 0.f};
                s = MFMA16(qa0, kb0, s);
                s = MFMA16(qa1, kb1, s);
                #pragma unroll
                for (int rr = 0; rr < 4; rr++) {
                    int q = 4 * g + rr;
                    int dnc = nc - (c0 + q);
                    bool ok = (nc >= 0) && (nc < IMGW) && (dnc >= -3) &&
                              (dnc <= ((w == 3) ? 0 : 3));
                    if (!ok) s[rr] = -FLTMAX;
                }
                sw[w][ct] = s;
            }
        }
    }

    float m[4] = {-FLTMAX, -FLTMAX, -FLTMAX, -FLTMAX};
    #pragma unroll
    for (int kt = 0; kt < 16; kt++)
        #pragma unroll
        for (int rr = 0; rr < 4; rr++) m[rr] = fmaxf(m[rr], st[kt][rr]);
    #pragma unroll
    for (int w = 0; w < 4; w++)
        if (wvalid[w])
            #pragma unroll
            for (int ct = 0; ct < 2; ct++)
                #pragma unroll
                for (int rr = 0; rr < 4; rr++) m[rr] = fmaxf(m[rr], sw[w][ct][rr]);
    #pragma unroll
    for (int rr = 0; rr < 4; rr++) {
        m[rr] = fmaxf(m[rr], __shfl_xor(m[rr], 1));
        m[rr] = fmaxf(m[rr], __shfl_xor(m[rr], 2));
        m[rr] = fmaxf(m[rr], __shfl_xor(m[rr], 4));
        m[rr] = fmaxf(m[rr], __shfl_xor(m[rr], 8));
    }
    float ssum[4] = {0.f, 0.f, 0.f, 0.f};
    #pragma unroll
    for (int kt = 0; kt < 16; kt++)
        #pragma unroll
        for (int rr = 0; rr < 4; rr++) {
            float e = expf(st[kt][rr] - m[rr]);
            st[kt][rr] = e;
            ssum[rr] += e;
        }
    #pragma unroll
    for (int w = 0; w < 4; w++)
        if (wvalid[w])
            #pragma unroll
            for (int ct = 0; ct < 2; ct++)
                #pragma unroll
                for (int rr = 0; rr < 4; rr++) {
                    float e = expf(sw[w][ct][rr] - m[rr]);
                    sw[w][ct][rr] = e;
                    ssum[rr] += e;
                }
    #pragma unroll
    for (int rr = 0; rr < 4; rr++) {
        ssum[rr] += __shfl_xor(ssum[rr], 1);
        ssum[rr] += __shfl_xor(ssum[rr], 2);
        ssum[rr] += __shfl_xor(ssum[rr], 4);
        ssum[rr] += __shfl_xor(ssum[rr], 8);
    }

    #pragma unroll
    for (int kt = 0; kt < 16; kt++)
        #pragma unroll
        for (int rr = 0; rr < 4; rr++)
            P[(4 * g + rr) * 392 + kt * 16 + col] = f2bf(st[kt][rr]);
    #pragma unroll
    for (int w = 0; w < 4; w++)
        if (wvalid[w])
            #pragma unroll
            for (int ct = 0; ct < 2; ct++)
                #pragma unroll
                for (int rr = 0; rr < 4; rr++)
                    P[(4 * g + rr) * 392 + 256 + w * 32 + ct * 16 + col] =
                        f2bf(sw[w][ct][rr]);
    __syncthreads();

    f32x4 acc[4] = {};
    #pragma unroll
    for (int kkb = 0; kkb < 8; kkb++) {
        short8 pa = *reinterpret_cast<const short8*>(&P[col * 392 + kkb * 32 + g * 8]);
        #pragma unroll
        for (int n0t = 0; n0t < 4; n0t++) {
            short8 vb = *reinterpret_cast<const short8*>(
                vt + ((size_t)bh * DH + n0t * 16 + col) * VTW + kkb * 32 + g * 8);
            acc[n0t] = MFMA16(pa, vb, acc[n0t]);
        }
    }
    #pragma unroll
    for (int w = 0; w < 4; w++) {
        if (wvalid[w]) {
            int nr = r - 3 + w;
            short8 pa = *reinterpret_cast<const short8*>(&P[col * 392 + 256 + w * 32 + g * 8]);
            size_t vkey = (size_t)(NTEXT + nr * IMGW + c0 - 8 + g * 8);
            #pragma unroll
            for (int n0t = 0; n0t < 4; n0t++) {
                short8 vb = *reinterpret_cast<const short8*>(
                    vt + ((size_t)bh * DH + n0t * 16 + col) * VTW + vkey);
                acc[n0t] = MFMA16(pa, vb, acc[n0t]);
            }
        }
    }

    #pragma unroll
    for (int rr = 0; rr < 4; rr++) {
        int qrow_o = NTEXT + r * IMGW + c0 + 4 * g + rr;
        float inv = 1.f / ssum[rr];
        #pragma unroll
        for (int n0t = 0; n0t < 4; n0t++)
            ao[((size_t)b * SEQ + qrow_o) * DIMD + h * DH + n0t * 16 + col] =
                f2bf(acc[n0t][rr] * inv);
    }
}

extern "C" void kernel_launch(void* const* d_in, const int* in_sizes, int n_in,
                              void* d_out, int out_size, void* d_ws, size_t ws_size,
                              hipStream_t stream) {
    const float* x    = (const float*)d_in[0];
    const int* mask   = (const int*)d_in[1];
    const float* Wqkv = (const float*)d_in[2];
    const float* Wout = (const float*)d_in[3];
    const float* bout = (const float*)d_in[4];
    float* out = (float*)d_out;

    unsigned short* ws = (unsigned short*)d_ws;
    const size_t XB  = (size_t)5120 * 512;          // 2.62M
    const size_t WQT = (size_t)1536 * 512;          // 0.79M
    const size_t WOT = (size_t)512 * 512;           // 0.26M
    const size_t PER = (size_t)BH * SEQ * DH;       // 2.62M
    const size_t VTE = (size_t)BH * DH * VTW;       // 2.75M
    unsigned short* xb    = ws;
    unsigned short* wqkvt = xb + XB;
    unsigned short* woutt = wqkvt + WQT;
    unsigned short* qb    = woutt + WOT;
    unsigned short* kb    = qb + PER;
    unsigned short* vt    = kb + PER;
    unsigned short* ao    = vt + VTE;               // [5120][512] bf16

    convert_x<<<dim3(1280), dim3(256), 0, stream>>>(x, xb);
    convert_transpose<<<dim3(8, 24), dim3(256), 0, stream>>>(Wqkv, wqkvt, 1536);
    convert_transpose<<<dim3(8, 8), dim3(256), 0, stream>>>(Wout, woutt, 512);
    mfma_gemm<0><<<dim3(40, 12), dim3(256), 0, stream>>>(
        xb, wqkvt, qb, kb, vt, nullptr, nullptr);
    attn_text2<<<dim3(BH * 16), dim3(64), 0, stream>>>(qb, kb, vt, ao);
    attn_img2<<<dim3(BH * 64), dim3(64), 0, stream>>>(qb, kb, vt, mask, ao);
    mfma_gemm<1><<<dim3(40, 4), dim3(256), 0, stream>>>(
        ao, woutt, nullptr, nullptr, nullptr, bout, out);
}

// Round 5
// 131.083 us; speedup vs baseline: 5.3754x; 1.1597x over previous
//
#include <hip/hip_runtime.h>
#include <math.h>

#define DIMD 512
#define SEQ 1280
#define NREAL 1279
#define NTEXT 256
#define NIMG 1024
#define IMGW 32
#define NH 8
#define DH 64
#define BH 32
#define BATCH 4
#define VTW 1344            // Vt padded key width (SEQ + 64)
#define FLTMAX 3.402823466e38f

typedef __attribute__((ext_vector_type(8))) short short8;
typedef __attribute__((ext_vector_type(4))) float f32x4;
typedef __attribute__((ext_vector_type(4))) unsigned short ushort4v;
typedef __attribute__((ext_vector_type(8))) unsigned short ushort8v;

#define MFMA16(a, b, c) __builtin_amdgcn_mfma_f32_16x16x32_bf16((a), (b), (c), 0, 0, 0)

__device__ __forceinline__ unsigned short f2bf(float x) {
    unsigned int u = __builtin_bit_cast(unsigned int, x);
    u += 0x7fffu + ((u >> 16) & 1u);
    return (unsigned short)(u >> 16);
}

__device__ __forceinline__ void gload16(const unsigned short* g, unsigned short* l) {
    __builtin_amdgcn_global_load_lds(
        (const __attribute__((address_space(1))) unsigned int*)g,
        (__attribute__((address_space(3))) unsigned int*)l,
        16, 0, 0);
}

// ---------------- Kernel 0: fused conversions ----------------
// blocks [0,1280): x f32 -> xb bf16 padded [5120][512]
// blocks [1280,1472): Wqkv transpose -> wqkvt [1536][512] bf16
// blocks [1472,1536): Wout transpose -> woutt [512][512] bf16
__global__ __launch_bounds__(256) void convert_fused(
    const float* __restrict__ x, const float* __restrict__ Wqkv,
    const float* __restrict__ Wout, unsigned short* __restrict__ xb,
    unsigned short* __restrict__ wqkvt, unsigned short* __restrict__ woutt)
{
    __shared__ unsigned short lds[64 * 65];
    const int blk = blockIdx.x;
    const int t = threadIdx.x;

    if (blk < 1280) {
        const size_t tt = (size_t)blk * 256 + t;
        const size_t e0 = tt * 8;
        const int row = (int)(e0 >> 9);
        const int d = (int)(e0 & 511);
        const int b = row / SEQ;
        const int ns = row - b * SEQ;
        ushort8v o;
        if (ns < NREAL) {
            const float4* p = reinterpret_cast<const float4*>(
                x + ((size_t)b * NREAL + ns) * DIMD + d);
            float4 v0 = p[0], v1 = p[1];
            o[0] = f2bf(v0.x); o[1] = f2bf(v0.y); o[2] = f2bf(v0.z); o[3] = f2bf(v0.w);
            o[4] = f2bf(v1.x); o[5] = f2bf(v1.y); o[6] = f2bf(v1.z); o[7] = f2bf(v1.w);
        } else {
            o = ushort8v{0, 0, 0, 0, 0, 0, 0, 0};
        }
        *reinterpret_cast<ushort8v*>(xb + e0) = o;
        return;
    }

    const bool isq = (blk < 1472);
    const int lb = blk - (isq ? 1280 : 1472);
    const float* W = isq ? Wqkv : Wout;
    unsigned short* Wt = isq ? wqkvt : woutt;
    const int N = isq ? 1536 : 512;
    const int k0 = (lb & 7) * 64, n0 = (lb >> 3) * 64;

    #pragma unroll
    for (int i = 0; i < 4; i++) {
        int idx = t + 256 * i;
        int r = idx >> 4, c4 = (idx & 15) * 4;
        float4 v = *reinterpret_cast<const float4*>(W + (size_t)(k0 + r) * N + n0 + c4);
        lds[(c4 + 0) * 65 + r] = f2bf(v.x);
        lds[(c4 + 1) * 65 + r] = f2bf(v.y);
        lds[(c4 + 2) * 65 + r] = f2bf(v.z);
        lds[(c4 + 3) * 65 + r] = f2bf(v.w);
    }
    __syncthreads();
    #pragma unroll
    for (int i = 0; i < 4; i++) {
        int idx = t + 256 * i;
        int n = idx >> 4, k4 = (idx & 15) * 4;
        ushort4v o;
        #pragma unroll
        for (int j = 0; j < 4; j++) o[j] = lds[n * 65 + k4 + j];
        *reinterpret_cast<ushort4v*>(Wt + (size_t)(n0 + n) * 512 + k0 + k4) = o;
    }
}

// ---------------- MFMA GEMM: C[TMxTN] = A[M][512] x Bt[N][512]^T ------------
// 4 waves in 2x2; wave computes (TM/2)x(TN/2).
// EPI 0: qkv routing epilogue; EPI 1: out = C + bias (rows < NREAL)
template<int TM, int TN, int EPI>
__global__ __launch_bounds__(256) void mfma_gemm(
    const unsigned short* __restrict__ A, const unsigned short* __restrict__ Bt,
    unsigned short* __restrict__ qb, unsigned short* __restrict__ kb,
    unsigned short* __restrict__ vt,
    const float* __restrict__ bias, float* __restrict__ out)
{
    constexpr int MI = TM / 32;
    constexpr int NI = TN / 32;
    __shared__ __align__(16) unsigned short As[TM * 64];
    __shared__ __align__(16) unsigned short Bs[TN * 64];
    const int tid = threadIdx.x;
    const int lane = tid & 63, w = tid >> 6;
    const int wm = w >> 1, wn = w & 1;
    const int g = lane >> 4, col = lane & 15;
    const int m0 = blockIdx.x * TM, n0 = blockIdx.y * TN;
    char* AsB = (char*)&As[0];
    char* BsB = (char*)&Bs[0];

    f32x4 acc[MI][NI] = {};

    for (int ks = 0; ks < 8; ks++) {
        const int k0 = ks * 64;
        #pragma unroll
        for (int j = 0; j < TM / 32; j++) {
            int rbase = w * (TM / 4) + j * 8;
            int r = rbase + (lane >> 3);
            int cs = (lane & 7) ^ (r & 7);
            gload16(A + (size_t)(m0 + r) * 512 + k0 + cs * 8,
                    (unsigned short*)(AsB + rbase * 128));
        }
        #pragma unroll
        for (int j = 0; j < TN / 32; j++) {
            int rbase = w * (TN / 4) + j * 8;
            int r = rbase + (lane >> 3);
            int cs = (lane & 7) ^ (r & 7);
            gload16(Bt + (size_t)(n0 + r) * 512 + k0 + cs * 8,
                    (unsigned short*)(BsB + rbase * 128));
        }
        __syncthreads();

        short8 af[MI][2], bfr[NI][2];
        #pragma unroll
        for (int mi = 0; mi < MI; mi++) {
            int rA = wm * (TM / 2) + mi * 16 + col;
            #pragma unroll
            for (int kk = 0; kk < 2; kk++) {
                int sl = (kk * 4 + g) ^ (rA & 7);
                af[mi][kk] = *reinterpret_cast<const short8*>(AsB + rA * 128 + sl * 16);
            }
        }
        #pragma unroll
        for (int ni = 0; ni < NI; ni++) {
            int rB = wn * (TN / 2) + ni * 16 + col;
            #pragma unroll
            for (int kk = 0; kk < 2; kk++) {
                int sl = (kk * 4 + g) ^ (rB & 7);
                bfr[ni][kk] = *reinterpret_cast<const short8*>(BsB + rB * 128 + sl * 16);
            }
        }
        #pragma unroll
        for (int kk = 0; kk < 2; kk++)
            #pragma unroll
            for (int mi = 0; mi < MI; mi++)
                #pragma unroll
                for (int ni = 0; ni < NI; ni++)
                    acc[mi][ni] = MFMA16(af[mi][kk], bfr[ni][kk], acc[mi][ni]);
        __syncthreads();
    }

    const int b = m0 / SEQ;
    const int nb = m0 - b * SEQ;

    if (EPI == 0) {
        #pragma unroll
        for (int ni = 0; ni < NI; ni++) {
            const int n = n0 + wn * (TN / 2) + ni * 16 + col;
            const int which = n >> 9;
            const int h = (n >> 6) & 7;
            const int dh = n & 63;
            const int bh = b * NH + h;
            #pragma unroll
            for (int mi = 0; mi < MI; mi++) {
                const int ns0 = nb + wm * (TM / 2) + mi * 16 + 4 * g;
                if (which == 2) {
                    ushort4v pk;
                    #pragma unroll
                    for (int rr = 0; rr < 4; rr++) pk[rr] = f2bf(acc[mi][ni][rr]);
                    *reinterpret_cast<ushort4v*>(
                        vt + ((size_t)bh * DH + dh) * VTW + ns0) = pk;
                } else {
                    unsigned short* dst = which ? kb : qb;
                    const float sc = which ? 1.f : 0.125f;
                    #pragma unroll
                    for (int rr = 0; rr < 4; rr++)
                        dst[((size_t)bh * SEQ + ns0 + rr) * DH + dh] =
                            f2bf(acc[mi][ni][rr] * sc);
                }
            }
        }
    } else {
        #pragma unroll
        for (int ni = 0; ni < NI; ni++) {
            const int n = n0 + wn * (TN / 2) + ni * 16 + col;
            const float bv = bias[n];
            #pragma unroll
            for (int mi = 0; mi < MI; mi++) {
                const int ns0 = nb + wm * (TM / 2) + mi * 16 + 4 * g;
                #pragma unroll
                for (int rr = 0; rr < 4; rr++) {
                    int ns = ns0 + rr;
                    if (ns < NREAL)
                        out[((size_t)b * NREAL + ns) * DIMD + n] = acc[mi][ni][rr] + bv;
                }
            }
        }
    }
}

// ---------------- Fused attention ----------------
__device__ __forceinline__ void attn_text_body(
    const unsigned short* __restrict__ qb, const unsigned short* __restrict__ kb,
    const unsigned short* __restrict__ vt, unsigned short* __restrict__ ao,
    unsigned short* P, int bh, int t, int lane)
{
    const int g = lane >> 4, col = lane & 15;
    const int b = bh >> 3, h = bh & 7;

    const size_t qrow = (size_t)bh * SEQ + t * 16 + col;
    const short8 qa0 = *reinterpret_cast<const short8*>(qb + qrow * DH + g * 8);
    const short8 qa1 = *reinterpret_cast<const short8*>(qb + qrow * DH + 32 + g * 8);

    f32x4 st[16];
    #pragma unroll
    for (int kt = 0; kt < 16; kt++) {
        if (kt <= t) {
            size_t krow = (size_t)bh * SEQ + kt * 16 + col;
            short8 kb0 = *reinterpret_cast<const short8*>(kb + krow * DH + g * 8);
            short8 kb1 = *reinterpret_cast<const short8*>(kb + krow * DH + 32 + g * 8);
            f32x4 s = {0.f, 0.f, 0.f, 0.f};
            s = MFMA16(qa0, kb0, s);
            s = MFMA16(qa1, kb1, s);
            if (kt == t) {
                #pragma unroll
                for (int rr = 0; rr < 4; rr++)
                    if (col > 4 * g + rr) s[rr] = -FLTMAX;
            }
            st[kt] = s;
        }
    }

    float m[4] = {-FLTMAX, -FLTMAX, -FLTMAX, -FLTMAX};
    #pragma unroll
    for (int kt = 0; kt < 16; kt++)
        if (kt <= t)
            #pragma unroll
            for (int rr = 0; rr < 4; rr++) m[rr] = fmaxf(m[rr], st[kt][rr]);
    #pragma unroll
    for (int rr = 0; rr < 4; rr++) {
        m[rr] = fmaxf(m[rr], __shfl_xor(m[rr], 1));
        m[rr] = fmaxf(m[rr], __shfl_xor(m[rr], 2));
        m[rr] = fmaxf(m[rr], __shfl_xor(m[rr], 4));
        m[rr] = fmaxf(m[rr], __shfl_xor(m[rr], 8));
    }
    float ssum[4] = {0.f, 0.f, 0.f, 0.f};
    #pragma unroll
    for (int kt = 0; kt < 16; kt++)
        if (kt <= t) {
            #pragma unroll
            for (int rr = 0; rr < 4; rr++) {
                float e = __expf(st[kt][rr] - m[rr]);
                st[kt][rr] = e;
                ssum[rr] += e;
            }
        }
    #pragma unroll
    for (int rr = 0; rr < 4; rr++) {
        ssum[rr] += __shfl_xor(ssum[rr], 1);
        ssum[rr] += __shfl_xor(ssum[rr], 2);
        ssum[rr] += __shfl_xor(ssum[rr], 4);
        ssum[rr] += __shfl_xor(ssum[rr], 8);
    }

    #pragma unroll
    for (int kt = 0; kt < 16; kt++)
        if (kt <= t) {
            #pragma unroll
            for (int rr = 0; rr < 4; rr++)
                P[(4 * g + rr) * 264 + kt * 16 + col] = f2bf(st[kt][rr]);
        }
    if ((t & 1) == 0) {
        ushort4v z = {0, 0, 0, 0};
        *reinterpret_cast<ushort4v*>(
            &P[(lane >> 2) * 264 + (t + 1) * 16 + (lane & 3) * 4]) = z;
    }
    __syncthreads();

    f32x4 acc[4] = {};
    #pragma unroll
    for (int kkb = 0; kkb < 8; kkb++) {
        if (kkb <= (t >> 1)) {
            short8 pa = *reinterpret_cast<const short8*>(&P[col * 264 + kkb * 32 + g * 8]);
            #pragma unroll
            for (int n0t = 0; n0t < 4; n0t++) {
                short8 vb = *reinterpret_cast<const short8*>(
                    vt + ((size_t)bh * DH + n0t * 16 + col) * VTW + kkb * 32 + g * 8);
                acc[n0t] = MFMA16(pa, vb, acc[n0t]);
            }
        }
    }

    #pragma unroll
    for (int rr = 0; rr < 4; rr++) {
        int qrow_o = t * 16 + 4 * g + rr;
        float inv = 1.f / ssum[rr];
        #pragma unroll
        for (int n0t = 0; n0t < 4; n0t++)
            ao[((size_t)b * SEQ + qrow_o) * DIMD + h * DH + n0t * 16 + col] =
                f2bf(acc[n0t][rr] * inv);
    }
}

__device__ __forceinline__ void attn_img_body(
    const unsigned short* __restrict__ qb, const unsigned short* __restrict__ kb,
    const unsigned short* __restrict__ vt, const int* __restrict__ mask,
    unsigned short* __restrict__ ao, unsigned short* P, int bh, int tile, int lane)
{
    const int r = tile >> 1, c0 = (tile & 1) << 4;
    const int g = lane >> 4, col = lane & 15;
    const int b = bh >> 3, h = bh & 7;

    const size_t qrow = (size_t)bh * SEQ + NTEXT + r * 32 + c0 + col;
    const short8 qa0 = *reinterpret_cast<const short8*>(qb + qrow * DH + g * 8);
    const short8 qa1 = *reinterpret_cast<const short8*>(qb + qrow * DH + 32 + g * 8);

    f32x4 st[16];
    #pragma unroll
    for (int kt = 0; kt < 16; kt++) {
        int j = kt * 16 + col;
        size_t krow = (size_t)bh * SEQ + j;
        short8 kb0 = *reinterpret_cast<const short8*>(kb + krow * DH + g * 8);
        short8 kb1 = *reinterpret_cast<const short8*>(kb + krow * DH + 32 + g * 8);
        f32x4 s = {0.f, 0.f, 0.f, 0.f};
        s = MFMA16(qa0, kb0, s);
        s = MFMA16(qa1, kb1, s);
        if (mask[b * 256 + j] == 0) {
            #pragma unroll
            for (int rr = 0; rr < 4; rr++) s[rr] = -FLTMAX;
        }
        st[kt] = s;
    }

    f32x4 sw[4][2];
    bool wvalid[4];
    #pragma unroll
    for (int w = 0; w < 4; w++) {
        int nr = r - 3 + w;
        wvalid[w] = (nr >= 0);
        if (nr >= 0) {
            #pragma unroll
            for (int ct = 0; ct < 2; ct++) {
                int nc = c0 - 8 + ct * 16 + col;
                int ncc = min(max(nc, 0), IMGW - 1);
                size_t krow = (size_t)bh * SEQ + NTEXT + nr * IMGW + ncc;
                short8 kb0 = *reinterpret_cast<const short8*>(kb + krow * DH + g * 8);
                short8 kb1 = *reinterpret_cast<const short8*>(kb + krow * DH + 32 + g * 8);
                f32x4 s = {0.f, 0.f, 0.f, 0.f};
                s = MFMA16(qa0, kb0, s);
                s = MFMA16(qa1, kb1, s);
                #pragma unroll
                for (int rr = 0; rr < 4; rr++) {
                    int q = 4 * g + rr;
                    int dnc = nc - (c0 + q);
                    bool ok = (nc >= 0) && (nc < IMGW) && (dnc >= -3) &&
                              (dnc <= ((w == 3) ? 0 : 3));
                    if (!ok) s[rr] = -FLTMAX;
                }
                sw[w][ct] = s;
            }
        }
    }

    float m[4] = {-FLTMAX, -FLTMAX, -FLTMAX, -FLTMAX};
    #pragma unroll
    for (int kt = 0; kt < 16; kt++)
        #pragma unroll
        for (int rr = 0; rr < 4; rr++) m[rr] = fmaxf(m[rr], st[kt][rr]);
    #pragma unroll
    for (int w = 0; w < 4; w++)
        if (wvalid[w])
            #pragma unroll
            for (int ct = 0; ct < 2; ct++)
                #pragma unroll
                for (int rr = 0; rr < 4; rr++) m[rr] = fmaxf(m[rr], sw[w][ct][rr]);
    #pragma unroll
    for (int rr = 0; rr < 4; rr++) {
        m[rr] = fmaxf(m[rr], __shfl_xor(m[rr], 1));
        m[rr] = fmaxf(m[rr], __shfl_xor(m[rr], 2));
        m[rr] = fmaxf(m[rr], __shfl_xor(m[rr], 4));
        m[rr] = fmaxf(m[rr], __shfl_xor(m[rr], 8));
    }
    float ssum[4] = {0.f, 0.f, 0.f, 0.f};
    #pragma unroll
    for (int kt = 0; kt < 16; kt++)
        #pragma unroll
        for (int rr = 0; rr < 4; rr++) {
            float e = __expf(st[kt][rr] - m[rr]);
            st[kt][rr] = e;
            ssum[rr] += e;
        }
    #pragma unroll
    for (int w = 0; w < 4; w++)
        if (wvalid[w])
            #pragma unroll
            for (int ct = 0; ct < 2; ct++)
                #pragma unroll
                for (int rr = 0; rr < 4; rr++) {
                    float e = __expf(sw[w][ct][rr] - m[rr]);
                    sw[w][ct][rr] = e;
                    ssum[rr] += e;
                }
    #pragma unroll
    for (int rr = 0; rr < 4; rr++) {
        ssum[rr] += __shfl_xor(ssum[rr], 1);
        ssum[rr] += __shfl_xor(ssum[rr], 2);
        ssum[rr] += __shfl_xor(ssum[rr], 4);
        ssum[rr] += __shfl_xor(ssum[rr], 8);
    }

    #pragma unroll
    for (int kt = 0; kt < 16; kt++)
        #pragma unroll
        for (int rr = 0; rr < 4; rr++)
            P[(4 * g + rr) * 392 + kt * 16 + col] = f2bf(st[kt][rr]);
    #pragma unroll
    for (int w = 0; w < 4; w++)
        if (wvalid[w])
            #pragma unroll
            for (int ct = 0; ct < 2; ct++)
                #pragma unroll
                for (int rr = 0; rr < 4; rr++)
                    P[(4 * g + rr) * 392 + 256 + w * 32 + ct * 16 + col] =
                        f2bf(sw[w][ct][rr]);
    __syncthreads();

    f32x4 acc[4] = {};
    #pragma unroll
    for (int kkb = 0; kkb < 8; kkb++) {
        short8 pa = *reinterpret_cast<const short8*>(&P[col * 392 + kkb * 32 + g * 8]);
        #pragma unroll
        for (int n0t = 0; n0t < 4; n0t++) {
            short8 vb = *reinterpret_cast<const short8*>(
                vt + ((size_t)bh * DH + n0t * 16 + col) * VTW + kkb * 32 + g * 8);
            acc[n0t] = MFMA16(pa, vb, acc[n0t]);
        }
    }
    #pragma unroll
    for (int w = 0; w < 4; w++) {
        if (wvalid[w]) {
            int nr = r - 3 + w;
            short8 pa = *reinterpret_cast<const short8*>(&P[col * 392 + 256 + w * 32 + g * 8]);
            size_t vkey = (size_t)(NTEXT + nr * IMGW + c0 - 8 + g * 8);
            #pragma unroll
            for (int n0t = 0; n0t < 4; n0t++) {
                short8 vb = *reinterpret_cast<const short8*>(
                    vt + ((size_t)bh * DH + n0t * 16 + col) * VTW + vkey);
                acc[n0t] = MFMA16(pa, vb, acc[n0t]);
            }
        }
    }

    #pragma unroll
    for (int rr = 0; rr < 4; rr++) {
        int qrow_o = NTEXT + r * IMGW + c0 + 4 * g + rr;
        float inv = 1.f / ssum[rr];
        #pragma unroll
        for (int n0t = 0; n0t < 4; n0t++)
            ao[((size_t)b * SEQ + qrow_o) * DIMD + h * DH + n0t * 16 + col] =
                f2bf(acc[n0t][rr] * inv);
    }
}

// blocks [0,512): text tiles; [512,2560): img tiles. 1 wave per block.
__global__ __launch_bounds__(64) void attn_fused(
    const unsigned short* __restrict__ qb, const unsigned short* __restrict__ kb,
    const unsigned short* __restrict__ vt, const int* __restrict__ mask,
    unsigned short* __restrict__ ao)
{
    __shared__ __align__(16) unsigned short P[16 * 392];
    const int blk = blockIdx.x;
    const int lane = threadIdx.x;
    if (blk < 512) {
        attn_text_body(qb, kb, vt, ao, P, blk >> 4, blk & 15, lane);
    } else {
        const int u = blk - 512;
        attn_img_body(qb, kb, vt, mask, ao, P, u >> 6, u & 63, lane);
    }
}

extern "C" void kernel_launch(void* const* d_in, const int* in_sizes, int n_in,
                              void* d_out, int out_size, void* d_ws, size_t ws_size,
                              hipStream_t stream) {
    const float* x    = (const float*)d_in[0];
    const int* mask   = (const int*)d_in[1];
    const float* Wqkv = (const float*)d_in[2];
    const float* Wout = (const float*)d_in[3];
    const float* bout = (const float*)d_in[4];
    float* out = (float*)d_out;

    unsigned short* ws = (unsigned short*)d_ws;
    const size_t XB  = (size_t)5120 * 512;
    const size_t WQT = (size_t)1536 * 512;
    const size_t WOT = (size_t)512 * 512;
    const size_t PER = (size_t)BH * SEQ * DH;
    const size_t VTE = (size_t)BH * DH * VTW;
    unsigned short* xb    = ws;
    unsigned short* wqkvt = xb + XB;
    unsigned short* woutt = wqkvt + WQT;
    unsigned short* qb    = woutt + WOT;
    unsigned short* kb    = qb + PER;
    unsigned short* vt    = kb + PER;
    unsigned short* ao    = vt + VTE;

    convert_fused<<<dim3(1536), dim3(256), 0, stream>>>(
        x, Wqkv, Wout, xb, wqkvt, woutt);
    mfma_gemm<64, 128, 0><<<dim3(80, 12), dim3(256), 0, stream>>>(
        xb, wqkvt, qb, kb, vt, nullptr, nullptr);
    attn_fused<<<dim3(2560), dim3(64), 0, stream>>>(qb, kb, vt, mask, ao);
    mfma_gemm<64, 64, 1><<<dim3(80, 8), dim3(256), 0, stream>>>(
        ao, woutt, nullptr, nullptr, nullptr, bout, out);
}

// Round 7
// 130.686 us; speedup vs baseline: 5.3918x; 1.0030x over previous
//
#include <hip/hip_runtime.h>
#include <math.h>

#define DIMD 512
#define SEQ 1280
#define NREAL 1279
#define NTEXT 256
#define NIMG 1024
#define IMGW 32
#define NH 8
#define DH 64
#define BH 32
#define BATCH 4
#define VTW 1344            // Vt padded key width (SEQ + 64)
#define PSTR 200            // compact-P LDS row stride (elems); 400B rows: 16B-aligned, 2-way banks
#define FLTMAX 3.402823466e38f

typedef __attribute__((ext_vector_type(8))) short short8;
typedef __attribute__((ext_vector_type(4))) float f32x4;
typedef __attribute__((ext_vector_type(4))) unsigned short ushort4v;
typedef __attribute__((ext_vector_type(8))) unsigned short ushort8v;

#define MFMA16(a, b, c) __builtin_amdgcn_mfma_f32_16x16x32_bf16((a), (b), (c), 0, 0, 0)

__device__ __forceinline__ unsigned short f2bf(float x) {
    unsigned int u = __builtin_bit_cast(unsigned int, x);
    u += 0x7fffu + ((u >> 16) & 1u);
    return (unsigned short)(u >> 16);
}

__device__ __forceinline__ void gload16(const unsigned short* g, unsigned short* l) {
    __builtin_amdgcn_global_load_lds(
        (const __attribute__((address_space(1))) unsigned int*)g,
        (__attribute__((address_space(3))) unsigned int*)l,
        16, 0, 0);
}

// ---------------- Kernel 0: fused conversions ----------------
__global__ __launch_bounds__(256) void convert_fused(
    const float* __restrict__ x, const float* __restrict__ Wqkv,
    const float* __restrict__ Wout, unsigned short* __restrict__ xb,
    unsigned short* __restrict__ wqkvt, unsigned short* __restrict__ woutt)
{
    __shared__ unsigned short lds[64 * 65];
    const int blk = blockIdx.x;
    const int t = threadIdx.x;

    if (blk < 1280) {
        const size_t tt = (size_t)blk * 256 + t;
        const size_t e0 = tt * 8;
        const int row = (int)(e0 >> 9);
        const int d = (int)(e0 & 511);
        const int b = row / SEQ;
        const int ns = row - b * SEQ;
        ushort8v o;
        if (ns < NREAL) {
            const float4* p = reinterpret_cast<const float4*>(
                x + ((size_t)b * NREAL + ns) * DIMD + d);
            float4 v0 = p[0], v1 = p[1];
            o[0] = f2bf(v0.x); o[1] = f2bf(v0.y); o[2] = f2bf(v0.z); o[3] = f2bf(v0.w);
            o[4] = f2bf(v1.x); o[5] = f2bf(v1.y); o[6] = f2bf(v1.z); o[7] = f2bf(v1.w);
        } else {
            o = ushort8v{0, 0, 0, 0, 0, 0, 0, 0};
        }
        *reinterpret_cast<ushort8v*>(xb + e0) = o;
        return;
    }

    const bool isq = (blk < 1472);
    const int lb = blk - (isq ? 1280 : 1472);
    const float* W = isq ? Wqkv : Wout;
    unsigned short* Wt = isq ? wqkvt : woutt;
    const int N = isq ? 1536 : 512;
    const int k0 = (lb & 7) * 64, n0 = (lb >> 3) * 64;

    #pragma unroll
    for (int i = 0; i < 4; i++) {
        int idx = t + 256 * i;
        int r = idx >> 4, c4 = (idx & 15) * 4;
        float4 v = *reinterpret_cast<const float4*>(W + (size_t)(k0 + r) * N + n0 + c4);
        lds[(c4 + 0) * 65 + r] = f2bf(v.x);
        lds[(c4 + 1) * 65 + r] = f2bf(v.y);
        lds[(c4 + 2) * 65 + r] = f2bf(v.z);
        lds[(c4 + 3) * 65 + r] = f2bf(v.w);
    }
    __syncthreads();
    #pragma unroll
    for (int i = 0; i < 4; i++) {
        int idx = t + 256 * i;
        int n = idx >> 4, k4 = (idx & 15) * 4;
        ushort4v o;
        #pragma unroll
        for (int j = 0; j < 4; j++) o[j] = lds[n * 65 + k4 + j];
        *reinterpret_cast<ushort4v*>(Wt + (size_t)(n0 + n) * 512 + k0 + k4) = o;
    }
}

// ---------------- MFMA GEMM (unchanged from R5) ----------------
template<int TM, int TN, int EPI>
__global__ __launch_bounds__(256) void mfma_gemm(
    const unsigned short* __restrict__ A, const unsigned short* __restrict__ Bt,
    unsigned short* __restrict__ qb, unsigned short* __restrict__ kb,
    unsigned short* __restrict__ vt,
    const float* __restrict__ bias, float* __restrict__ out)
{
    constexpr int MI = TM / 32;
    constexpr int NI = TN / 32;
    __shared__ __align__(16) unsigned short As[TM * 64];
    __shared__ __align__(16) unsigned short Bs[TN * 64];
    const int tid = threadIdx.x;
    const int lane = tid & 63, w = tid >> 6;
    const int wm = w >> 1, wn = w & 1;
    const int g = lane >> 4, col = lane & 15;
    const int m0 = blockIdx.x * TM, n0 = blockIdx.y * TN;
    char* AsB = (char*)&As[0];
    char* BsB = (char*)&Bs[0];

    f32x4 acc[MI][NI] = {};

    for (int ks = 0; ks < 8; ks++) {
        const int k0 = ks * 64;
        #pragma unroll
        for (int j = 0; j < TM / 32; j++) {
            int rbase = w * (TM / 4) + j * 8;
            int r = rbase + (lane >> 3);
            int cs = (lane & 7) ^ (r & 7);
            gload16(A + (size_t)(m0 + r) * 512 + k0 + cs * 8,
                    (unsigned short*)(AsB + rbase * 128));
        }
        #pragma unroll
        for (int j = 0; j < TN / 32; j++) {
            int rbase = w * (TN / 4) + j * 8;
            int r = rbase + (lane >> 3);
            int cs = (lane & 7) ^ (r & 7);
            gload16(Bt + (size_t)(n0 + r) * 512 + k0 + cs * 8,
                    (unsigned short*)(BsB + rbase * 128));
        }
        __syncthreads();

        short8 af[MI][2], bfr[NI][2];
        #pragma unroll
        for (int mi = 0; mi < MI; mi++) {
            int rA = wm * (TM / 2) + mi * 16 + col;
            #pragma unroll
            for (int kk = 0; kk < 2; kk++) {
                int sl = (kk * 4 + g) ^ (rA & 7);
                af[mi][kk] = *reinterpret_cast<const short8*>(AsB + rA * 128 + sl * 16);
            }
        }
        #pragma unroll
        for (int ni = 0; ni < NI; ni++) {
            int rB = wn * (TN / 2) + ni * 16 + col;
            #pragma unroll
            for (int kk = 0; kk < 2; kk++) {
                int sl = (kk * 4 + g) ^ (rB & 7);
                bfr[ni][kk] = *reinterpret_cast<const short8*>(BsB + rB * 128 + sl * 16);
            }
        }
        #pragma unroll
        for (int kk = 0; kk < 2; kk++)
            #pragma unroll
            for (int mi = 0; mi < MI; mi++)
                #pragma unroll
                for (int ni = 0; ni < NI; ni++)
                    acc[mi][ni] = MFMA16(af[mi][kk], bfr[ni][kk], acc[mi][ni]);
        __syncthreads();
    }

    const int b = m0 / SEQ;
    const int nb = m0 - b * SEQ;

    if (EPI == 0) {
        #pragma unroll
        for (int ni = 0; ni < NI; ni++) {
            const int n = n0 + wn * (TN / 2) + ni * 16 + col;
            const int which = n >> 9;
            const int h = (n >> 6) & 7;
            const int dh = n & 63;
            const int bh = b * NH + h;
            #pragma unroll
            for (int mi = 0; mi < MI; mi++) {
                const int ns0 = nb + wm * (TM / 2) + mi * 16 + 4 * g;
                if (which == 2) {
                    ushort4v pk;
                    #pragma unroll
                    for (int rr = 0; rr < 4; rr++) pk[rr] = f2bf(acc[mi][ni][rr]);
                    *reinterpret_cast<ushort4v*>(
                        vt + ((size_t)bh * DH + dh) * VTW + ns0) = pk;
                } else {
                    unsigned short* dst = which ? kb : qb;
                    const float sc = which ? 1.f : 0.125f;
                    #pragma unroll
                    for (int rr = 0; rr < 4; rr++)
                        dst[((size_t)bh * SEQ + ns0 + rr) * DH + dh] =
                            f2bf(acc[mi][ni][rr] * sc);
                }
            }
        }
    } else {
        #pragma unroll
        for (int ni = 0; ni < NI; ni++) {
            const int n = n0 + wn * (TN / 2) + ni * 16 + col;
            const float bv = bias[n];
            #pragma unroll
            for (int mi = 0; mi < MI; mi++) {
                const int ns0 = nb + wm * (TM / 2) + mi * 16 + 4 * g;
                #pragma unroll
                for (int rr = 0; rr < 4; rr++) {
                    int ns = ns0 + rr;
                    if (ns < NREAL)
                        out[((size_t)b * NREAL + ns) * DIMD + n] = acc[mi][ni][rr] + bv;
                }
            }
        }
    }
}

// ---------------- Split-K attention: 2 waves per 16-query tile ----------------
// blocks [0,512): text tile (bh, t): wave0 = even K-tiles, wave1 = odd K-tiles.
// blocks [512,2560): img tile: wave w = {text kt parity w} + {window rows 2w,2w+1}.
// Each wave: local softmax (own max) + partial PV; merged via LDS at the end.
__global__ __launch_bounds__(128) void attn_split(
    const unsigned short* __restrict__ qb, const unsigned short* __restrict__ kb,
    const unsigned short* __restrict__ vt, const int* __restrict__ mask,
    unsigned short* __restrict__ ao)
{
    __shared__ __align__(16) unsigned short P[2][16 * PSTR];
    __shared__ float OB[2][16][64];
    __shared__ float OM[2][16];
    __shared__ float OS[2][16];

    const int blk = blockIdx.x;
    const int tid = threadIdx.x;
    const int wid = tid >> 6, lane = tid & 63;
    const int g = lane >> 4, col = lane & 15;
    unsigned short* Pw = &P[wid][0];

    int bh, qbase;
    float m[4] = {-FLTMAX, -FLTMAX, -FLTMAX, -FLTMAX};
    float s[4] = {0.f, 0.f, 0.f, 0.f};
    f32x4 acc[4] = {};

    if (blk < 512) {
        // ---------------- text tile ----------------
        bh = blk >> 4;
        const int t = blk & 15;
        qbase = t * 16;
        const size_t qrow = (size_t)bh * SEQ + qbase + col;
        const short8 qa0 = *reinterpret_cast<const short8*>(qb + qrow * DH + g * 8);
        const short8 qa1 = *reinterpret_cast<const short8*>(qb + qrow * DH + 32 + g * 8);

        const int nkt = (t >= wid) ? ((t - wid) >> 1) + 1 : 0;
        f32x4 st[8];
        #pragma unroll
        for (int i = 0; i < 8; i++) {
            int kt = 2 * i + wid;
            if (i < nkt) {
                size_t krow = (size_t)bh * SEQ + kt * 16 + col;
                short8 kb0 = *reinterpret_cast<const short8*>(kb + krow * DH + g * 8);
                short8 kb1 = *reinterpret_cast<const short8*>(kb + krow * DH + 32 + g * 8);
                f32x4 sv = {0.f, 0.f, 0.f, 0.f};
                sv = MFMA16(qa0, kb0, sv);
                sv = MFMA16(qa1, kb1, sv);
                if (kt == t) {
                    #pragma unroll
                    for (int rr = 0; rr < 4; rr++)
                        if (col > 4 * g + rr) sv[rr] = -FLTMAX;
                }
                st[i] = sv;
            }
        }
        #pragma unroll
        for (int i = 0; i < 8; i++)
            if (i < nkt)
                #pragma unroll
                for (int rr = 0; rr < 4; rr++) m[rr] = fmaxf(m[rr], st[i][rr]);
        #pragma unroll
        for (int rr = 0; rr < 4; rr++) {
            m[rr] = fmaxf(m[rr], __shfl_xor(m[rr], 1));
            m[rr] = fmaxf(m[rr], __shfl_xor(m[rr], 2));
            m[rr] = fmaxf(m[rr], __shfl_xor(m[rr], 4));
            m[rr] = fmaxf(m[rr], __shfl_xor(m[rr], 8));
        }
        #pragma unroll
        for (int i = 0; i < 8; i++)
            if (i < nkt) {
                #pragma unroll
                for (int rr = 0; rr < 4; rr++) {
                    float e = __expf(st[i][rr] - m[rr]);
                    st[i][rr] = e;
                    s[rr] += e;
                }
            }
        #pragma unroll
        for (int rr = 0; rr < 4; rr++) {
            s[rr] += __shfl_xor(s[rr], 1);
            s[rr] += __shfl_xor(s[rr], 2);
            s[rr] += __shfl_xor(s[rr], 4);
            s[rr] += __shfl_xor(s[rr], 8);
        }
        #pragma unroll
        for (int i = 0; i < 8; i++)
            if (i < nkt)
                #pragma unroll
                for (int rr = 0; rr < 4; rr++)
                    Pw[(4 * g + rr) * PSTR + i * 16 + col] = f2bf(st[i][rr]);
        if (nkt & 1) {
            ushort4v z = {0, 0, 0, 0};
            *reinterpret_cast<ushort4v*>(
                &Pw[(lane >> 2) * PSTR + nkt * 16 + (lane & 3) * 4]) = z;
        }
        const int nck = (nkt + 1) >> 1;
        #pragma unroll
        for (int ck = 0; ck < 4; ck++) {
            if (ck < nck) {
                short8 pa = *reinterpret_cast<const short8*>(
                    Pw + col * PSTR + ck * 32 + g * 8);
                const int key_base = ck * 64 + (g >> 1) * 32 + wid * 16 + (g & 1) * 8;
                #pragma unroll
                for (int n0t = 0; n0t < 4; n0t++) {
                    short8 vb = *reinterpret_cast<const short8*>(
                        vt + ((size_t)bh * DH + n0t * 16 + col) * VTW + key_base);
                    acc[n0t] = MFMA16(pa, vb, acc[n0t]);
                }
            }
        }
    } else {
        // ---------------- img tile ----------------
        const int u = blk - 512;
        bh = u >> 6;
        const int tile = u & 63;
        const int r = tile >> 1, c0 = (tile & 1) << 4;
        qbase = NTEXT + r * IMGW + c0;
        const int b0 = bh >> 3;
        const size_t qrow = (size_t)bh * SEQ + qbase + col;
        const short8 qa0 = *reinterpret_cast<const short8*>(qb + qrow * DH + g * 8);
        const short8 qa1 = *reinterpret_cast<const short8*>(qb + qrow * DH + 32 + g * 8);

        // text keys, parity wid
        f32x4 st[8];
        #pragma unroll
        for (int i = 0; i < 8; i++) {
            int j = (2 * i + wid) * 16 + col;
            size_t krow = (size_t)bh * SEQ + j;
            short8 kb0 = *reinterpret_cast<const short8*>(kb + krow * DH + g * 8);
            short8 kb1 = *reinterpret_cast<const short8*>(kb + krow * DH + 32 + g * 8);
            f32x4 sv = {0.f, 0.f, 0.f, 0.f};
            sv = MFMA16(qa0, kb0, sv);
            sv = MFMA16(qa1, kb1, sv);
            if (mask[b0 * 256 + j] == 0) {
                #pragma unroll
                for (int rr = 0; rr < 4; rr++) sv[rr] = -FLTMAX;
            }
            st[i] = sv;
        }
        // window rows 2*wid, 2*wid+1
        f32x4 sw[2][2];
        bool wv[2];
        #pragma unroll
        for (int wi = 0; wi < 2; wi++) {
            const int wg = 2 * wid + wi;
            const int nr = r - 3 + wg;
            wv[wi] = (nr >= 0);
            if (wv[wi]) {
                #pragma unroll
                for (int ct = 0; ct < 2; ct++) {
                    int nc = c0 - 8 + ct * 16 + col;
                    int ncc = min(max(nc, 0), IMGW - 1);
                    size_t krow = (size_t)bh * SEQ + NTEXT + nr * IMGW + ncc;
                    short8 kb0 = *reinterpret_cast<const short8*>(kb + krow * DH + g * 8);
                    short8 kb1 = *reinterpret_cast<const short8*>(kb + krow * DH + 32 + g * 8);
                    f32x4 sv = {0.f, 0.f, 0.f, 0.f};
                    sv = MFMA16(qa0, kb0, sv);
                    sv = MFMA16(qa1, kb1, sv);
                    #pragma unroll
                    for (int rr = 0; rr < 4; rr++) {
                        int q = 4 * g + rr;
                        int dnc = nc - (c0 + q);
                        bool ok = (nc >= 0) && (nc < IMGW) && (dnc >= -3) &&
                                  (dnc <= ((wg == 3) ? 0 : 3));
                        if (!ok) sv[rr] = -FLTMAX;
                    }
                    sw[wi][ct] = sv;
                }
            }
        }
        // local softmax
        #pragma unroll
        for (int i = 0; i < 8; i++)
            #pragma unroll
            for (int rr = 0; rr < 4; rr++) m[rr] = fmaxf(m[rr], st[i][rr]);
        #pragma unroll
        for (int wi = 0; wi < 2; wi++)
            if (wv[wi])
                #pragma unroll
                for (int ct = 0; ct < 2; ct++)
                    #pragma unroll
                    for (int rr = 0; rr < 4; rr++) m[rr] = fmaxf(m[rr], sw[wi][ct][rr]);
        #pragma unroll
        for (int rr = 0; rr < 4; rr++) {
            m[rr] = fmaxf(m[rr], __shfl_xor(m[rr], 1));
            m[rr] = fmaxf(m[rr], __shfl_xor(m[rr], 2));
            m[rr] = fmaxf(m[rr], __shfl_xor(m[rr], 4));
            m[rr] = fmaxf(m[rr], __shfl_xor(m[rr], 8));
        }
        #pragma unroll
        for (int i = 0; i < 8; i++)
            #pragma unroll
            for (int rr = 0; rr < 4; rr++) {
                float e = __expf(st[i][rr] - m[rr]);
                st[i][rr] = e;
                s[rr] += e;
            }
        #pragma unroll
        for (int wi = 0; wi < 2; wi++)
            if (wv[wi])
                #pragma unroll
                for (int ct = 0; ct < 2; ct++)
                    #pragma unroll
                    for (int rr = 0; rr < 4; rr++) {
                        float e = __expf(sw[wi][ct][rr] - m[rr]);
                        sw[wi][ct][rr] = e;
                        s[rr] += e;
                    }
        #pragma unroll
        for (int rr = 0; rr < 4; rr++) {
            s[rr] += __shfl_xor(s[rr], 1);
            s[rr] += __shfl_xor(s[rr], 2);
            s[rr] += __shfl_xor(s[rr], 4);
            s[rr] += __shfl_xor(s[rr], 8);
        }
        // P: text at cols [0,128), window at [128,192)
        #pragma unroll
        for (int i = 0; i < 8; i++)
            #pragma unroll
            for (int rr = 0; rr < 4; rr++)
                Pw[(4 * g + rr) * PSTR + i * 16 + col] = f2bf(st[i][rr]);
        #pragma unroll
        for (int wi = 0; wi < 2; wi++)
            if (wv[wi])
                #pragma unroll
                for (int ct = 0; ct < 2; ct++)
                    #pragma unroll
                    for (int rr = 0; rr < 4; rr++)
                        Pw[(4 * g + rr) * PSTR + 128 + wi * 32 + ct * 16 + col] =
                            f2bf(sw[wi][ct][rr]);
        // PV: text
        #pragma unroll
        for (int ck = 0; ck < 4; ck++) {
            short8 pa = *reinterpret_cast<const short8*>(
                Pw + col * PSTR + ck * 32 + g * 8);
            const int key_base = ck * 64 + (g >> 1) * 32 + wid * 16 + (g & 1) * 8;
            #pragma unroll
            for (int n0t = 0; n0t < 4; n0t++) {
                short8 vb = *reinterpret_cast<const short8*>(
                    vt + ((size_t)bh * DH + n0t * 16 + col) * VTW + key_base);
                acc[n0t] = MFMA16(pa, vb, acc[n0t]);
            }
        }
        // PV: window
        #pragma unroll
        for (int wi = 0; wi < 2; wi++) {
            if (wv[wi]) {
                const int nr = r - 3 + 2 * wid + wi;
                short8 pa = *reinterpret_cast<const short8*>(
                    Pw + col * PSTR + 128 + wi * 32 + g * 8);
                const size_t vkey = (size_t)(NTEXT + nr * IMGW + c0 - 8 + g * 8);
                #pragma unroll
                for (int n0t = 0; n0t < 4; n0t++) {
                    short8 vb = *reinterpret_cast<const short8*>(
                        vt + ((size_t)bh * DH + n0t * 16 + col) * VTW + vkey);
                    acc[n0t] = MFMA16(pa, vb, acc[n0t]);
                }
            }
        }
    }

    // per-wave partials -> LDS
    #pragma unroll
    for (int rr = 0; rr < 4; rr++) {
        #pragma unroll
        for (int n0t = 0; n0t < 4; n0t++)
            OB[wid][4 * g + rr][n0t * 16 + col] = acc[n0t][rr];
        if (col == 0) {
            OM[wid][4 * g + rr] = m[rr];
            OS[wid][4 * g + rr] = s[rr];
        }
    }
    __syncthreads();

    // merge + write (16 q x 8 d-groups over 128 threads)
    const int q = tid >> 3, d0 = (tid & 7) * 8;
    const float m0 = OM[0][q], m1 = OM[1][q];
    const float M = fmaxf(m0, m1);
    const float f0 = __expf(m0 - M), f1 = __expf(m1 - M);
    const float inv = 1.f / (OS[0][q] * f0 + OS[1][q] * f1);
    ushort8v o;
    #pragma unroll
    for (int e = 0; e < 8; e++) {
        float v = (OB[0][q][d0 + e] * f0 + OB[1][q][d0 + e] * f1) * inv;
        o[e] = f2bf(v);
    }
    const int b = bh >> 3, h = bh & 7;
    *reinterpret_cast<ushort8v*>(
        ao + ((size_t)b * SEQ + qbase + q) * DIMD + h * DH + d0) = o;
}

extern "C" void kernel_launch(void* const* d_in, const int* in_sizes, int n_in,
                              void* d_out, int out_size, void* d_ws, size_t ws_size,
                              hipStream_t stream) {
    const float* x    = (const float*)d_in[0];
    const int* mask   = (const int*)d_in[1];
    const float* Wqkv = (const float*)d_in[2];
    const float* Wout = (const float*)d_in[3];
    const float* bout = (const float*)d_in[4];
    float* out = (float*)d_out;

    unsigned short* ws = (unsigned short*)d_ws;
    const size_t XB  = (size_t)5120 * 512;
    const size_t WQT = (size_t)1536 * 512;
    const size_t WOT = (size_t)512 * 512;
    const size_t PER = (size_t)BH * SEQ * DH;
    const size_t VTE = (size_t)BH * DH * VTW;
    unsigned short* xb    = ws;
    unsigned short* wqkvt = xb + XB;
    unsigned short* woutt = wqkvt + WQT;
    unsigned short* qb    = woutt + WOT;
    unsigned short* kb    = qb + PER;
    unsigned short* vt    = kb + PER;
    unsigned short* ao    = vt + VTE;

    convert_fused<<<dim3(1536), dim3(256), 0, stream>>>(
        x, Wqkv, Wout, xb, wqkvt, woutt);
    mfma_gemm<64, 128, 0><<<dim3(80, 12), dim3(256), 0, stream>>>(
        xb, wqkvt, qb, kb, vt, nullptr, nullptr);
    attn_split<<<dim3(2560), dim3(128), 0, stream>>>(qb, kb, vt, mask, ao);
    mfma_gemm<64, 64, 1><<<dim3(80, 8), dim3(256), 0, stream>>>(
        ao, woutt, nullptr, nullptr, nullptr, bout, out);
}